// Round 8
// baseline (266.844 us; speedup 1.0000x reference)
//
#include <hip/hip_runtime.h>
#include <hip/hip_bf16.h>
#include <stdint.h>

#define N_NODES 10000
#define N_EDGES 160000

typedef unsigned short u16;
typedef unsigned int u32;
typedef short s16v8 __attribute__((ext_vector_type(8)));
typedef float f32v4 __attribute__((ext_vector_type(4)));

__device__ __forceinline__ float bf2f(u16 v){ return __uint_as_float(((u32)v) << 16); }
__device__ __forceinline__ u16 f2bf(float f){
    u32 u = __float_as_uint(f);
    u32 r = (u + 0x7fffu + ((u >> 16) & 1u)) >> 16;
    return (u16)r;
}

// ---------------- weights fp32->bf16 (+tconv transpose to [d][o][c]) + graph init ----------------
struct SmallPtrs { const void* p[14]; };

__device__ __constant__ const int g_seg_off[15] = {
    0, 12288, 12416, 16512, 16576, 41152, 41280,
    65856, 65984, 70080, 70144, 94720, 94848, 104064, 104076
};
// 0=straight, 1=tconv CIN=32 transpose, 2=tconv CIN=64 transpose
__device__ __constant__ const int g_seg_kind[14] = {
    1, 0, 0, 0, 2, 0, 2, 0, 0, 0, 2, 0, 0, 0
};

__global__ void k_convert_init(SmallPtrs ps, u16* __restrict__ dst,
                               float* deg, int* cnt, int* cur){
    int i = blockIdx.x * blockDim.x + threadIdx.x;
    if (i < 104076){
        int seg = 0, base = 0;
#pragma unroll
        for (int s = 0; s < 14; s++){
            if (i >= g_seg_off[s]){ seg = s; base = g_seg_off[s]; }
        }
        int li = i - base;
        float v = ((const float*)ps.p[seg])[li];
        int kind = g_seg_kind[seg];
        int dsto = li;
        if (kind){
            int CIN = (kind == 1) ? 32 : 64;
            int o = li / (3 * CIN);
            int rem = li - o * (3 * CIN);
            int c = rem / 3, d = rem - c * 3;
            dsto = d * 128 * CIN + o * CIN + c;     // [d][o][c]
        }
        dst[base + dsto] = f2bf(v);
    }
    if (i < N_NODES){ deg[i] = 1.0f; cnt[i] = 0; cur[i] = 0; }
}

// ---------------- merged: gconv32 (blocks 0..1249) || edge count (blocks 1250..1874) ----------------
__launch_bounds__(256, 2)
__global__ void k_gconv_count(const float* __restrict__ xin, const u16* __restrict__ wg,
                              const u16* __restrict__ bg, u16* __restrict__ out,
                              const int* __restrict__ ei, const float* __restrict__ ew,
                              float* deg, int* cnt){
    if (blockIdx.x >= 1250){
        int e = (blockIdx.x - 1250) * 256 + threadIdx.x;
        if (e < N_EDGES){
            int d = ei[N_EDGES + e];
            atomicAdd(&deg[d], ew[e]);
            atomicAdd(&cnt[d], 1);
        }
        return;
    }
    __shared__ __attribute__((aligned(16))) u16 xT[8][14][40];
    __shared__ __attribute__((aligned(16))) u16 Ho[8][12][72];
    int tid = threadIdx.x;
    int n0 = blockIdx.x * 8;

    for (int i = tid; i < 8 * 40; i += 256){
        int g = i / 40, c = i % 40;
        xT[g][0][c] = 0; xT[g][13][c] = 0;
    }
    {
        int g = tid >> 5, c = tid & 31;
        const float4* p = (const float4*)(xin + ((size_t)(n0 + g) * 32 + c) * 12);
        float4 v0 = p[0], v1 = p[1], v2 = p[2];
        xT[g][1][c] = f2bf(v0.x);  xT[g][2][c] = f2bf(v0.y);
        xT[g][3][c] = f2bf(v0.z);  xT[g][4][c] = f2bf(v0.w);
        xT[g][5][c] = f2bf(v1.x);  xT[g][6][c] = f2bf(v1.y);
        xT[g][7][c] = f2bf(v1.z);  xT[g][8][c] = f2bf(v1.w);
        xT[g][9][c] = f2bf(v2.x);  xT[g][10][c] = f2bf(v2.y);
        xT[g][11][c] = f2bf(v2.z); xT[g][12][c] = f2bf(v2.w);
    }
    int lane = tid & 63, wave = tid >> 6;
    int col = lane & 15, quad = lane >> 4;
    int o_p = wave * 16 + col, o_q = o_p + 64;

    s16v8 Bf[3][2];
#pragma unroll
    for (int pq = 0; pq < 2; pq++){
        int o = pq ? o_q : o_p;
#pragma unroll
        for (int d = 0; d < 3; d++)
            Bf[d][pq] = *(const s16v8*)(wg + d * 4096 + o * 32 + quad * 8);
    }
    __syncthreads();

    f32v4 aP[6], aQ[6];
#pragma unroll
    for (int mt = 0; mt < 6; mt++){ aP[mt] = (f32v4)0.f; aQ[mt] = (f32v4)0.f; }
#pragma unroll
    for (int mt = 0; mt < 6; mt++){
        int m = mt * 16 + col;
        int g = m / 12, t = m - 12 * g;
#pragma unroll
        for (int d = 0; d < 3; d++){
            s16v8 a = *(const s16v8*)&xT[g][t + d][quad * 8];
            aP[mt] = __builtin_amdgcn_mfma_f32_16x16x32_bf16(a, Bf[d][0], aP[mt], 0, 0, 0);
            aQ[mt] = __builtin_amdgcn_mfma_f32_16x16x32_bf16(a, Bf[d][1], aQ[mt], 0, 0, 0);
        }
    }
    float bP = bf2f(bg[o_p]), bQ = bf2f(bg[o_q]);
#pragma unroll
    for (int mt = 0; mt < 6; mt++){
#pragma unroll
        for (int r = 0; r < 4; r++){
            int m2 = mt * 16 + quad * 4 + r;
            int g = m2 / 12, t = m2 - 12 * g;
            float pv = aP[mt][r] + bP, qv = aQ[mt][r] + bQ;
            Ho[g][t][o_p] = f2bf(pv / (1.f + __expf(-qv)));
        }
    }
    __syncthreads();
    for (int i = tid; i < 768; i += 256){
        int g = i / 96, r = i % 96, t = r / 8, ch = r % 8;
        *(s16v8*)(out + (size_t)(n0 + g) * 768 + t * 64 + ch * 8) = *(const s16v8*)&Ho[g][t][ch * 8];
    }
}

// single-pass scan (shuffle-based) + dis, one block of 1024
__global__ void k_scan_dis(const int* __restrict__ cnt, int* __restrict__ off,
                           const float* __restrict__ deg, float* __restrict__ dis){
    __shared__ int wsum[16], woff[16];
    int t = threadIdx.x;
    int lane = t & 63, wv = t >> 6;
    int base = t * 10;
    int loc[10];
    int mysum = 0;
    if (base < N_NODES){
#pragma unroll
        for (int j = 0; j < 10; j++){ loc[j] = mysum; mysum += cnt[base + j]; }
    }
    int s = mysum;
#pragma unroll
    for (int d = 1; d < 64; d <<= 1){
        int v = __shfl_up(s, d, 64);
        if (lane >= d) s += v;
    }
    if (lane == 63) wsum[wv] = s;
    __syncthreads();
    if (t < 16){
        int v = wsum[t];
        int sc = v;
#pragma unroll
        for (int d = 1; d < 16; d <<= 1){
            int u = __shfl_up(sc, d, 16);
            if (t >= d) sc += u;
        }
        woff[t] = sc - v;
        if (t == 15) off[N_NODES] = sc;
    }
    __syncthreads();
    int tbase = woff[wv] + (s - mysum);
    if (base < N_NODES){
#pragma unroll
        for (int j = 0; j < 10; j++) off[base + j] = tbase + loc[j];
    }
    for (int i = t; i < N_NODES; i += 1024) dis[i] = rsqrtf(deg[i]);
}

__global__ void k_scatter(const int* __restrict__ ei, const float* __restrict__ ew,
                          const float* __restrict__ dis, const int* __restrict__ off,
                          int* cur, int2* __restrict__ epack){
    int e = blockIdx.x * blockDim.x + threadIdx.x;
    if (e < N_EDGES){
        int s = ei[e];
        int d = ei[N_EDGES + e];
        float nw = dis[s] * ew[e] * dis[d];
        int p = off[d] + atomicAdd(&cur[d], 1);
        epack[p] = make_int2(s, __float_as_int(nw));
    }
}

// ---------------- slice-partitioned GCN gather: z = dis^2*x + sum norm*x[src] ----------------
// slice = blockIdx % 8 (XCD round-robin): per-XCD working set = 10000 * 192 B ~ 1.9 MB -> L2-resident.
// 32 nodes/block, 8 lanes/node, 12 elems (24 B) per lane.
__launch_bounds__(256, 8)
__global__ void k_gather(const u16* __restrict__ src, const float* __restrict__ dis,
                         const int* __restrict__ off, const int2* __restrict__ ep,
                         u16* __restrict__ z){
    int slice = blockIdx.x & 7;
    int nb = blockIdx.x >> 3;
    int nl = threadIdx.x >> 3;
    int l8 = threadIdx.x & 7;
    int n = nb * 32 + nl;
    if (n >= N_NODES) return;
    int base = slice * 96 + l8 * 12;
    const u16* xr = src + (size_t)n * 768 + base;
    float dv = dis[n];
    float sw = dv * dv;
    float acc[12];
#pragma unroll
    for (int k = 0; k < 3; k++){
        ushort4 v = *(const ushort4*)(xr + k * 4);
        acc[k * 4 + 0] = sw * bf2f(v.x); acc[k * 4 + 1] = sw * bf2f(v.y);
        acc[k * 4 + 2] = sw * bf2f(v.z); acc[k * 4 + 3] = sw * bf2f(v.w);
    }
    int b = off[n], e = off[n + 1];
    int p = b;
    for (; p + 1 < e; p += 2){
        int2 e0 = ep[p], e1 = ep[p + 1];
        float w0 = __int_as_float(e0.y), w1 = __int_as_float(e1.y);
        const u16* q0 = src + (size_t)e0.x * 768 + base;
        const u16* q1 = src + (size_t)e1.x * 768 + base;
        ushort4 a0 = *(const ushort4*)(q0);
        ushort4 a1 = *(const ushort4*)(q0 + 4);
        ushort4 a2 = *(const ushort4*)(q0 + 8);
        ushort4 c0 = *(const ushort4*)(q1);
        ushort4 c1 = *(const ushort4*)(q1 + 4);
        ushort4 c2 = *(const ushort4*)(q1 + 8);
        acc[0] = fmaf(w0, bf2f(a0.x), acc[0]); acc[1] = fmaf(w0, bf2f(a0.y), acc[1]);
        acc[2] = fmaf(w0, bf2f(a0.z), acc[2]); acc[3] = fmaf(w0, bf2f(a0.w), acc[3]);
        acc[4] = fmaf(w0, bf2f(a1.x), acc[4]); acc[5] = fmaf(w0, bf2f(a1.y), acc[5]);
        acc[6] = fmaf(w0, bf2f(a1.z), acc[6]); acc[7] = fmaf(w0, bf2f(a1.w), acc[7]);
        acc[8] = fmaf(w0, bf2f(a2.x), acc[8]); acc[9] = fmaf(w0, bf2f(a2.y), acc[9]);
        acc[10] = fmaf(w0, bf2f(a2.z), acc[10]); acc[11] = fmaf(w0, bf2f(a2.w), acc[11]);
        acc[0] = fmaf(w1, bf2f(c0.x), acc[0]); acc[1] = fmaf(w1, bf2f(c0.y), acc[1]);
        acc[2] = fmaf(w1, bf2f(c0.z), acc[2]); acc[3] = fmaf(w1, bf2f(c0.w), acc[3]);
        acc[4] = fmaf(w1, bf2f(c1.x), acc[4]); acc[5] = fmaf(w1, bf2f(c1.y), acc[5]);
        acc[6] = fmaf(w1, bf2f(c1.z), acc[6]); acc[7] = fmaf(w1, bf2f(c1.w), acc[7]);
        acc[8] = fmaf(w1, bf2f(c2.x), acc[8]); acc[9] = fmaf(w1, bf2f(c2.y), acc[9]);
        acc[10] = fmaf(w1, bf2f(c2.z), acc[10]); acc[11] = fmaf(w1, bf2f(c2.w), acc[11]);
    }
    if (p < e){
        int2 e0 = ep[p];
        float w0 = __int_as_float(e0.y);
        const u16* q0 = src + (size_t)e0.x * 768 + base;
#pragma unroll
        for (int k = 0; k < 3; k++){
            ushort4 v = *(const ushort4*)(q0 + k * 4);
            acc[k * 4 + 0] = fmaf(w0, bf2f(v.x), acc[k * 4 + 0]);
            acc[k * 4 + 1] = fmaf(w0, bf2f(v.y), acc[k * 4 + 1]);
            acc[k * 4 + 2] = fmaf(w0, bf2f(v.z), acc[k * 4 + 2]);
            acc[k * 4 + 3] = fmaf(w0, bf2f(v.w), acc[k * 4 + 3]);
        }
    }
    u16* zo = z + (size_t)n * 768 + base;
#pragma unroll
    for (int k = 0; k < 3; k++){
        ushort4 hv;
        hv.x = f2bf(acc[k * 4 + 0]); hv.y = f2bf(acc[k * 4 + 1]);
        hv.z = f2bf(acc[k * 4 + 2]); hv.w = f2bf(acc[k * 4 + 3]);
        *(ushort4*)(zo + k * 4) = hv;
    }
}

// ---------------- fused: stage z -> mix(relu) -> gconv w1 -> (MID: gconv w2 | LAST: final) ----------------
// 4 nodes/block.
#define XIDX(g, row, c) (((g) * 14 + (row)) * 72 + (c))

template<bool LAST>
__launch_bounds__(256, 8)
__global__ void k_fused(const u16* __restrict__ z,      // [n][t*64+c] bf16 (pre-aggregated)
                        const u16* __restrict__ Wmix, const u16* __restrict__ bmix,
                        const u16* __restrict__ w1, const u16* __restrict__ b1,
                        const u16* __restrict__ w2, const u16* __restrict__ b2,
                        const u16* __restrict__ fw, const u16* __restrict__ fb,
                        u16* __restrict__ outMid, float* __restrict__ outFin){
    __shared__ __attribute__((aligned(16))) u16 bufX[4 * 14 * 72];
    __shared__ __attribute__((aligned(16))) u16 bufY[4 * 14 * 72];
    int tid = threadIdx.x;
    int n0 = blockIdx.x * 4;
    int lane = tid & 63, wave = tid >> 6;
    int col = lane & 15, quad = lane >> 4;

    // zero time-pad rows
    for (int i = tid; i < 4 * 72; i += 256){
        int g = i / 72, c = i % 72;
        bufX[XIDX(g, 0, c)] = 0; bufX[XIDX(g, 13, c)] = 0;
        bufY[XIDX(g, 0, c)] = 0; bufY[XIDX(g, 13, c)] = 0;
    }
    // stage z -> bufX rows 1..12
    for (int i = tid; i < 384; i += 256){
        int g = i / 96, r = i % 96, t = r >> 3, ch = r & 7;
        *(s16v8*)&bufX[XIDX(g, 1 + t, ch * 8)] =
            *(const s16v8*)(z + (size_t)(n0 + g) * 768 + t * 64 + ch * 8);
    }
    // ---- mix B frags ----
    int o_mix = wave * 16 + col;
    s16v8 Bm[2];
#pragma unroll
    for (int ks = 0; ks < 2; ks++)
        Bm[ks] = *(const s16v8*)(Wmix + (size_t)o_mix * 64 + ks * 32 + quad * 8);
    __syncthreads();

    // ---- mix MFMA: y = relu(z*W + b) ----
    {
        f32v4 accm[3];
#pragma unroll
        for (int mt = 0; mt < 3; mt++) accm[mt] = (f32v4)0.f;
#pragma unroll
        for (int mt = 0; mt < 3; mt++){
            int m = mt * 16 + col;
            int g = m / 12, t = m - 12 * g;
#pragma unroll
            for (int ks = 0; ks < 2; ks++){
                s16v8 a = *(const s16v8*)&bufX[XIDX(g, 1 + t, ks * 32 + quad * 8)];
                accm[mt] = __builtin_amdgcn_mfma_f32_16x16x32_bf16(a, Bm[ks], accm[mt], 0, 0, 0);
            }
        }
        float bm = bf2f(bmix[o_mix]);
#pragma unroll
        for (int mt = 0; mt < 3; mt++){
#pragma unroll
            for (int r = 0; r < 4; r++){
                int m2 = mt * 16 + quad * 4 + r;
                int g = m2 / 12, t = m2 - 12 * g;
                bufY[XIDX(g, 1 + t, o_mix)] = f2bf(fmaxf(accm[mt][r] + bm, 0.f));
            }
        }
    }
    __syncthreads();

    // ---- gated conv 1: bufY -> bufX ----
    {
        int o_p = wave * 16 + col, o_q = o_p + 64;
        s16v8 Bf[3][2][2];
#pragma unroll
        for (int pq = 0; pq < 2; pq++){
            int o = pq ? o_q : o_p;
#pragma unroll
            for (int d = 0; d < 3; d++)
#pragma unroll
                for (int ks = 0; ks < 2; ks++)
                    Bf[d][ks][pq] = *(const s16v8*)(w1 + d * 8192 + o * 64 + ks * 32 + quad * 8);
        }
        f32v4 aP[3], aQ[3];
#pragma unroll
        for (int mt = 0; mt < 3; mt++){ aP[mt] = (f32v4)0.f; aQ[mt] = (f32v4)0.f; }
#pragma unroll
        for (int mt = 0; mt < 3; mt++){
            int m = mt * 16 + col;
            int g = m / 12, t = m - 12 * g;
#pragma unroll
            for (int d = 0; d < 3; d++)
#pragma unroll
                for (int ks = 0; ks < 2; ks++){
                    s16v8 a = *(const s16v8*)&bufY[XIDX(g, t + d, ks * 32 + quad * 8)];
                    aP[mt] = __builtin_amdgcn_mfma_f32_16x16x32_bf16(a, Bf[d][ks][0], aP[mt], 0, 0, 0);
                    aQ[mt] = __builtin_amdgcn_mfma_f32_16x16x32_bf16(a, Bf[d][ks][1], aQ[mt], 0, 0, 0);
                }
        }
        float bP = bf2f(b1[o_p]), bQ = bf2f(b1[o_q]);
#pragma unroll
        for (int mt = 0; mt < 3; mt++){
#pragma unroll
            for (int r = 0; r < 4; r++){
                int m2 = mt * 16 + quad * 4 + r;
                int g = m2 / 12, t = m2 - 12 * g;
                float pv = aP[mt][r] + bP, qv = aQ[mt][r] + bQ;
                u16 hv = f2bf(pv / (1.f + __expf(-qv)));
                if (LAST) bufX[g * 1008 + o_p * 12 + t] = hv;   // H2[g][c*12+t]
                else      bufX[XIDX(g, 1 + t, o_p)] = hv;
            }
        }
    }
    __syncthreads();

    if (!LAST){
        // ---- gated conv 2: bufX -> bufY -> outMid ----
        int o_p = wave * 16 + col, o_q = o_p + 64;
        s16v8 Bf[3][2][2];
#pragma unroll
        for (int pq = 0; pq < 2; pq++){
            int o = pq ? o_q : o_p;
#pragma unroll
            for (int d = 0; d < 3; d++)
#pragma unroll
                for (int ks = 0; ks < 2; ks++)
                    Bf[d][ks][pq] = *(const s16v8*)(w2 + d * 8192 + o * 64 + ks * 32 + quad * 8);
        }
        f32v4 aP[3], aQ[3];
#pragma unroll
        for (int mt = 0; mt < 3; mt++){ aP[mt] = (f32v4)0.f; aQ[mt] = (f32v4)0.f; }
#pragma unroll
        for (int mt = 0; mt < 3; mt++){
            int m = mt * 16 + col;
            int g = m / 12, t = m - 12 * g;
#pragma unroll
            for (int d = 0; d < 3; d++)
#pragma unroll
                for (int ks = 0; ks < 2; ks++){
                    s16v8 a = *(const s16v8*)&bufX[XIDX(g, t + d, ks * 32 + quad * 8)];
                    aP[mt] = __builtin_amdgcn_mfma_f32_16x16x32_bf16(a, Bf[d][ks][0], aP[mt], 0, 0, 0);
                    aQ[mt] = __builtin_amdgcn_mfma_f32_16x16x32_bf16(a, Bf[d][ks][1], aQ[mt], 0, 0, 0);
                }
        }
        float bP = bf2f(b2[o_p]), bQ = bf2f(b2[o_q]);
#pragma unroll
        for (int mt = 0; mt < 3; mt++){
#pragma unroll
            for (int r = 0; r < 4; r++){
                int m2 = mt * 16 + quad * 4 + r;
                int g = m2 / 12, t = m2 - 12 * g;
                float pv = aP[mt][r] + bP, qv = aQ[mt][r] + bQ;
                bufY[XIDX(g, 1 + t, o_p)] = f2bf(pv / (1.f + __expf(-qv)));
            }
        }
        __syncthreads();
        for (int i = tid; i < 384; i += 256){
            int g = i / 96, r = i % 96, t = r / 8, ch = r % 8;
            *(s16v8*)(outMid + (size_t)(n0 + g) * 768 + t * 64 + ch * 8) =
                *(const s16v8*)&bufY[XIDX(g, 1 + t, ch * 8)];
        }
    } else {
        // ---- final: out[g][o] = sum_k H2[g][k]*fw[o][k] + fb[o] (wave 0) ----
        if (wave == 0){
            f32v4 accF = {0.f, 0.f, 0.f, 0.f};
            int g4 = col & 3;
#pragma unroll
            for (int ks = 0; ks < 24; ks++){
                s16v8 a = *(const s16v8*)&bufX[g4 * 1008 + ks * 32 + quad * 8];
                s16v8 bfr = {0, 0, 0, 0, 0, 0, 0, 0};
                if (col < 12)
                    bfr = *(const s16v8*)(fw + (size_t)col * 768 + ks * 32 + quad * 8);
                accF = __builtin_amdgcn_mfma_f32_16x16x32_bf16(a, bfr, accF, 0, 0, 0);
            }
            if (col < 12 && quad == 0){
                float bb = bf2f(fb[col]);
#pragma unroll
                for (int r = 0; r < 4; r++){
                    outFin[(size_t)(n0 + r) * 12 + col] = accF[r] + bb;
                }
            }
        }
    }
}

// ---------------- launch ----------------
static inline size_t align256(size_t x){ return (x + 255) & ~(size_t)255; }

extern "C" void kernel_launch(void* const* d_in, const int* in_sizes, int n_in,
                              void* d_out, int out_size, void* d_ws, size_t ws_size,
                              hipStream_t stream){
    const float* x  = (const float*)d_in[0];
    const int* ei   = (const int*)d_in[1];
    const float* ew = (const float*)d_in[2];

    char* w = (char*)d_ws;
    u16* bufA    = (u16*)w;  w += align256((size_t)N_NODES * 768 * sizeof(u16));
    u16* bufB    = (u16*)w;  w += align256((size_t)N_NODES * 768 * sizeof(u16));
    u16* zA      = (u16*)w;  w += align256((size_t)N_NODES * 768 * sizeof(u16));
    u16* zB      = (u16*)w;  w += align256((size_t)N_NODES * 768 * sizeof(u16));
    float* deg   = (float*)w; w += align256(N_NODES * sizeof(float));
    float* dis   = (float*)w; w += align256(N_NODES * sizeof(float));
    int* cnt     = (int*)w;   w += align256(N_NODES * sizeof(int));
    int* off     = (int*)w;   w += align256((N_NODES + 1) * sizeof(int));
    int* cur     = (int*)w;   w += align256(N_NODES * sizeof(int));
    int2* epack  = (int2*)w;  w += align256((size_t)N_EDGES * sizeof(int2));
    u16* cvt     = (u16*)w;   w += align256(104076 * sizeof(u16));

    u16* tc1a_w = cvt + 0;        // [d][128][32]
    u16* tc1a_b = cvt + 12288;
    u16* gc1_w  = cvt + 12416;
    u16* gc1_b  = cvt + 16512;
    u16* tc1b_w = cvt + 16576;    // [d][128][64]
    u16* tc1b_b = cvt + 41152;
    u16* tc2a_w = cvt + 41280;    // [d][128][64]
    u16* tc2a_b = cvt + 65856;
    u16* gc2_w  = cvt + 65984;
    u16* gc2_b  = cvt + 70080;
    u16* tc2b_w = cvt + 70144;    // [d][128][64]
    u16* tc2b_b = cvt + 94720;
    u16* fin_w  = cvt + 94848;
    u16* fin_b  = cvt + 104064;

    SmallPtrs ps;
    ps.p[0]  = d_in[3];  ps.p[1]  = d_in[4];
    ps.p[2]  = d_in[5];  ps.p[3]  = d_in[6];
    ps.p[4]  = d_in[7];  ps.p[5]  = d_in[8];
    ps.p[6]  = d_in[9];  ps.p[7]  = d_in[10];
    ps.p[8]  = d_in[11]; ps.p[9]  = d_in[12];
    ps.p[10] = d_in[13]; ps.p[11] = d_in[14];
    ps.p[12] = d_in[15]; ps.p[13] = d_in[16];

    k_convert_init<<<(104076 + 255) / 256, 256, 0, stream>>>(ps, cvt, deg, cnt, cur);
    k_gconv_count<<<1250 + 625, 256, 0, stream>>>(x, tc1a_w, tc1a_b, bufA, ei, ew, deg, cnt);
    k_scan_dis<<<1, 1024, 0, stream>>>(cnt, off, deg, dis);
    k_scatter<<<625, 256, 0, stream>>>(ei, ew, dis, off, cur, epack);

    k_gather<<<313 * 8, 256, 0, stream>>>(bufA, dis, off, epack, zA);
    k_fused<false><<<2500, 256, 0, stream>>>(zA, gc1_w, gc1_b, tc1b_w, tc1b_b,
                                             tc2a_w, tc2a_b, nullptr, nullptr,
                                             bufB, nullptr);
    k_gather<<<313 * 8, 256, 0, stream>>>(bufB, dis, off, epack, zB);
    k_fused<true><<<2500, 256, 0, stream>>>(zB, gc2_w, gc2_b, tc2b_w, tc2b_b,
                                            nullptr, nullptr, fin_w, fin_b,
                                            nullptr, (float*)d_out);
}

// Round 9
// 261.577 us; speedup vs baseline: 1.0201x; 1.0201x over previous
//
#include <hip/hip_runtime.h>
#include <hip/hip_bf16.h>
#include <stdint.h>

#define N_NODES 10000
#define N_EDGES 160000
#define BUCKET 128

typedef unsigned short u16;
typedef unsigned int u32;
typedef short s16v8 __attribute__((ext_vector_type(8)));
typedef float f32v4 __attribute__((ext_vector_type(4)));

__device__ __forceinline__ float bf2f(u16 v){ return __uint_as_float(((u32)v) << 16); }
__device__ __forceinline__ u16 f2bf(float f){
    u32 u = __float_as_uint(f);
    u32 r = (u + 0x7fffu + ((u >> 16) & 1u)) >> 16;
    return (u16)r;
}

// ---------------- weights fp32->bf16 (+tconv transpose to [d][o][c]) + graph init ----------------
struct SmallPtrs { const void* p[14]; };

__device__ __constant__ const int g_seg_off[15] = {
    0, 12288, 12416, 16512, 16576, 41152, 41280,
    65856, 65984, 70080, 70144, 94720, 94848, 104064, 104076
};
// 0=straight, 1=tconv CIN=32 transpose, 2=tconv CIN=64 transpose
__device__ __constant__ const int g_seg_kind[14] = {
    1, 0, 0, 0, 2, 0, 2, 0, 0, 0, 2, 0, 0, 0
};

__global__ void k_convert_init(SmallPtrs ps, u16* __restrict__ dst,
                               float* deg, int* cur){
    int i = blockIdx.x * blockDim.x + threadIdx.x;
    if (i < 104076){
        int seg = 0, base = 0;
#pragma unroll
        for (int s = 0; s < 14; s++){
            if (i >= g_seg_off[s]){ seg = s; base = g_seg_off[s]; }
        }
        int li = i - base;
        float v = ((const float*)ps.p[seg])[li];
        int kind = g_seg_kind[seg];
        int dsto = li;
        if (kind){
            int CIN = (kind == 1) ? 32 : 64;
            int o = li / (3 * CIN);
            int rem = li - o * (3 * CIN);
            int c = rem / 3, d = rem - c * 3;
            dsto = d * 128 * CIN + o * CIN + c;     // [d][o][c]
        }
        dst[base + dsto] = f2bf(v);
    }
    if (i < N_NODES){ deg[i] = 1.0f; cur[i] = 0; }
}

// ---------------- merged: gconv32 (blocks 0..1249) || deg accumulation (blocks 1250..1874) ----------------
__launch_bounds__(256, 2)
__global__ void k_gconv_count(const float* __restrict__ xin, const u16* __restrict__ wg,
                              const u16* __restrict__ bg, u16* __restrict__ out,
                              const int* __restrict__ ei, const float* __restrict__ ew,
                              float* deg){
    if (blockIdx.x >= 1250){
        int e = (blockIdx.x - 1250) * 256 + threadIdx.x;
        if (e < N_EDGES){
            int d = ei[N_EDGES + e];
            atomicAdd(&deg[d], ew[e]);
        }
        return;
    }
    __shared__ __attribute__((aligned(16))) u16 xT[8][14][40];
    __shared__ __attribute__((aligned(16))) u16 Ho[8][12][72];
    int tid = threadIdx.x;
    int n0 = blockIdx.x * 8;

    int lane = tid & 63, wave = tid >> 6;
    int col = lane & 15, quad = lane >> 4;
    int o_p = wave * 16 + col, o_q = o_p + 64;

    // hoisted B frags
    s16v8 Bf[3][2];
#pragma unroll
    for (int pq = 0; pq < 2; pq++){
        int o = pq ? o_q : o_p;
#pragma unroll
        for (int d = 0; d < 3; d++)
            Bf[d][pq] = *(const s16v8*)(wg + d * 4096 + o * 32 + quad * 8);
    }

    for (int i = tid; i < 8 * 40; i += 256){
        int g = i / 40, c = i % 40;
        xT[g][0][c] = 0; xT[g][13][c] = 0;
    }
    {
        int g = tid >> 5, c = tid & 31;
        const float4* p = (const float4*)(xin + ((size_t)(n0 + g) * 32 + c) * 12);
        float4 v0 = p[0], v1 = p[1], v2 = p[2];
        xT[g][1][c] = f2bf(v0.x);  xT[g][2][c] = f2bf(v0.y);
        xT[g][3][c] = f2bf(v0.z);  xT[g][4][c] = f2bf(v0.w);
        xT[g][5][c] = f2bf(v1.x);  xT[g][6][c] = f2bf(v1.y);
        xT[g][7][c] = f2bf(v1.z);  xT[g][8][c] = f2bf(v1.w);
        xT[g][9][c] = f2bf(v2.x);  xT[g][10][c] = f2bf(v2.y);
        xT[g][11][c] = f2bf(v2.z); xT[g][12][c] = f2bf(v2.w);
    }
    __syncthreads();

    f32v4 aP[6], aQ[6];
#pragma unroll
    for (int mt = 0; mt < 6; mt++){ aP[mt] = (f32v4)0.f; aQ[mt] = (f32v4)0.f; }
#pragma unroll
    for (int mt = 0; mt < 6; mt++){
        int m = mt * 16 + col;
        int g = m / 12, t = m - 12 * g;
#pragma unroll
        for (int d = 0; d < 3; d++){
            s16v8 a = *(const s16v8*)&xT[g][t + d][quad * 8];
            aP[mt] = __builtin_amdgcn_mfma_f32_16x16x32_bf16(a, Bf[d][0], aP[mt], 0, 0, 0);
            aQ[mt] = __builtin_amdgcn_mfma_f32_16x16x32_bf16(a, Bf[d][1], aQ[mt], 0, 0, 0);
        }
    }
    float bP = bf2f(bg[o_p]), bQ = bf2f(bg[o_q]);
#pragma unroll
    for (int mt = 0; mt < 6; mt++){
#pragma unroll
        for (int r = 0; r < 4; r++){
            int m2 = mt * 16 + quad * 4 + r;
            int g = m2 / 12, t = m2 - 12 * g;
            float pv = aP[mt][r] + bP, qv = aQ[mt][r] + bQ;
            Ho[g][t][o_p] = f2bf(pv / (1.f + __expf(-qv)));
        }
    }
    __syncthreads();
    for (int i = tid; i < 768; i += 256){
        int g = i / 96, r = i % 96, t = r / 8, ch = r % 8;
        *(s16v8*)(out + (size_t)(n0 + g) * 768 + t * 64 + ch * 8) = *(const s16v8*)&Ho[g][t][ch * 8];
    }
}

// ---------------- bucketed CSR scatter (no scan needed) ----------------
__global__ void k_scatter(const int* __restrict__ ei, const float* __restrict__ ew,
                          const float* __restrict__ deg, int* cur, int2* __restrict__ epack){
    int e = blockIdx.x * blockDim.x + threadIdx.x;
    if (e < N_EDGES){
        int s = ei[e];
        int d = ei[N_EDGES + e];
        float nw = rsqrtf(deg[s]) * ew[e] * rsqrtf(deg[d]);
        int p = atomicAdd(&cur[d], 1);
        if (p < BUCKET) epack[d * BUCKET + p] = make_int2(s, __float_as_int(nw));
    }
}

// ---------------- slice-partitioned GCN gather: z = (1/deg)*x + sum norm*x[src] ----------------
// slice = blockIdx % 8 (XCD round-robin): per-XCD feature slice ~1.9 MB -> L2-resident.
__launch_bounds__(256, 6)
__global__ void k_gather(const u16* __restrict__ src, const float* __restrict__ deg,
                         const int* __restrict__ cur, const int2* __restrict__ ep,
                         u16* __restrict__ z){
    int slice = blockIdx.x & 7;
    int nb = blockIdx.x >> 3;
    int nl = threadIdx.x >> 3;
    int l8 = threadIdx.x & 7;
    int n = nb * 32 + nl;
    if (n >= N_NODES) return;
    int base = slice * 96 + l8 * 12;
    const u16* xr = src + (size_t)n * 768 + base;
    float sw = 1.0f / deg[n];
    float acc[12];
#pragma unroll
    for (int k = 0; k < 3; k++){
        ushort4 v = *(const ushort4*)(xr + k * 4);
        acc[k * 4 + 0] = sw * bf2f(v.x); acc[k * 4 + 1] = sw * bf2f(v.y);
        acc[k * 4 + 2] = sw * bf2f(v.z); acc[k * 4 + 3] = sw * bf2f(v.w);
    }
    int e = cur[n]; if (e > BUCKET) e = BUCKET;
    const int2* eb = ep + (size_t)n * BUCKET;
    int p = 0;
    for (; p + 1 < e; p += 2){
        int2 e0 = eb[p], e1 = eb[p + 1];
        float w0 = __int_as_float(e0.y), w1 = __int_as_float(e1.y);
        const u16* q0 = src + (size_t)e0.x * 768 + base;
        const u16* q1 = src + (size_t)e1.x * 768 + base;
        ushort4 a0 = *(const ushort4*)(q0);
        ushort4 a1 = *(const ushort4*)(q0 + 4);
        ushort4 a2 = *(const ushort4*)(q0 + 8);
        ushort4 c0 = *(const ushort4*)(q1);
        ushort4 c1 = *(const ushort4*)(q1 + 4);
        ushort4 c2 = *(const ushort4*)(q1 + 8);
        acc[0] = fmaf(w0, bf2f(a0.x), acc[0]); acc[1] = fmaf(w0, bf2f(a0.y), acc[1]);
        acc[2] = fmaf(w0, bf2f(a0.z), acc[2]); acc[3] = fmaf(w0, bf2f(a0.w), acc[3]);
        acc[4] = fmaf(w0, bf2f(a1.x), acc[4]); acc[5] = fmaf(w0, bf2f(a1.y), acc[5]);
        acc[6] = fmaf(w0, bf2f(a1.z), acc[6]); acc[7] = fmaf(w0, bf2f(a1.w), acc[7]);
        acc[8] = fmaf(w0, bf2f(a2.x), acc[8]); acc[9] = fmaf(w0, bf2f(a2.y), acc[9]);
        acc[10] = fmaf(w0, bf2f(a2.z), acc[10]); acc[11] = fmaf(w0, bf2f(a2.w), acc[11]);
        acc[0] = fmaf(w1, bf2f(c0.x), acc[0]); acc[1] = fmaf(w1, bf2f(c0.y), acc[1]);
        acc[2] = fmaf(w1, bf2f(c0.z), acc[2]); acc[3] = fmaf(w1, bf2f(c0.w), acc[3]);
        acc[4] = fmaf(w1, bf2f(c1.x), acc[4]); acc[5] = fmaf(w1, bf2f(c1.y), acc[5]);
        acc[6] = fmaf(w1, bf2f(c1.z), acc[6]); acc[7] = fmaf(w1, bf2f(c1.w), acc[7]);
        acc[8] = fmaf(w1, bf2f(c2.x), acc[8]); acc[9] = fmaf(w1, bf2f(c2.y), acc[9]);
        acc[10] = fmaf(w1, bf2f(c2.z), acc[10]); acc[11] = fmaf(w1, bf2f(c2.w), acc[11]);
    }
    if (p < e){
        int2 e0 = eb[p];
        float w0 = __int_as_float(e0.y);
        const u16* q0 = src + (size_t)e0.x * 768 + base;
#pragma unroll
        for (int k = 0; k < 3; k++){
            ushort4 v = *(const ushort4*)(q0 + k * 4);
            acc[k * 4 + 0] = fmaf(w0, bf2f(v.x), acc[k * 4 + 0]);
            acc[k * 4 + 1] = fmaf(w0, bf2f(v.y), acc[k * 4 + 1]);
            acc[k * 4 + 2] = fmaf(w0, bf2f(v.z), acc[k * 4 + 2]);
            acc[k * 4 + 3] = fmaf(w0, bf2f(v.w), acc[k * 4 + 3]);
        }
    }
    u16* zo = z + (size_t)n * 768 + base;
#pragma unroll
    for (int k = 0; k < 3; k++){
        ushort4 hv;
        hv.x = f2bf(acc[k * 4 + 0]); hv.y = f2bf(acc[k * 4 + 1]);
        hv.z = f2bf(acc[k * 4 + 2]); hv.w = f2bf(acc[k * 4 + 3]);
        *(ushort4*)(zo + k * 4) = hv;
    }
}

// ---------------- fused: stage z -> mix(relu) -> gconv w1 -> (MID: gconv w2 | LAST: final) ----------------
// 4 nodes/block; ALL B-fragments hoisted to kernel entry (held in registers across phases).
#define XIDX(g, row, c) (((g) * 14 + (row)) * 72 + (c))

template<bool LAST>
__launch_bounds__(256, 4)
__global__ void k_fused(const u16* __restrict__ z,      // [n][t*64+c] bf16 (pre-aggregated)
                        const u16* __restrict__ Wmix, const u16* __restrict__ bmix,
                        const u16* __restrict__ w1, const u16* __restrict__ b1,
                        const u16* __restrict__ w2, const u16* __restrict__ b2,
                        const u16* __restrict__ fw, const u16* __restrict__ fb,
                        u16* __restrict__ outMid, float* __restrict__ outFin){
    __shared__ __attribute__((aligned(16))) u16 bufX[4 * 14 * 72];
    __shared__ __attribute__((aligned(16))) u16 bufY[4 * 14 * 72];
    int tid = threadIdx.x;
    int n0 = blockIdx.x * 4;
    int lane = tid & 63, wave = tid >> 6;
    int col = lane & 15, quad = lane >> 4;
    int o_p = wave * 16 + col, o_q = o_p + 64;
    int o_mix = o_p;

    // ---- hoisted B-frag loads: keep resident across all phases ----
    s16v8 Bm[2];
#pragma unroll
    for (int ks = 0; ks < 2; ks++)
        Bm[ks] = *(const s16v8*)(Wmix + (size_t)o_mix * 64 + ks * 32 + quad * 8);
    s16v8 Bf1[3][2][2];
#pragma unroll
    for (int pq = 0; pq < 2; pq++){
        int o = pq ? o_q : o_p;
#pragma unroll
        for (int d = 0; d < 3; d++)
#pragma unroll
            for (int ks = 0; ks < 2; ks++)
                Bf1[d][ks][pq] = *(const s16v8*)(w1 + d * 8192 + o * 64 + ks * 32 + quad * 8);
    }
    s16v8 Bf2[3][2][2];
    if (!LAST){
#pragma unroll
        for (int pq = 0; pq < 2; pq++){
            int o = pq ? o_q : o_p;
#pragma unroll
            for (int d = 0; d < 3; d++)
#pragma unroll
                for (int ks = 0; ks < 2; ks++)
                    Bf2[d][ks][pq] = *(const s16v8*)(w2 + d * 8192 + o * 64 + ks * 32 + quad * 8);
        }
    }
    float bmv = bf2f(bmix[o_mix]);
    float b1P = bf2f(b1[o_p]), b1Q = bf2f(b1[o_q]);
    float b2P = 0.f, b2Q = 0.f;
    if (!LAST){ b2P = bf2f(b2[o_p]); b2Q = bf2f(b2[o_q]); }

    // zero time-pad rows
    for (int i = tid; i < 4 * 72; i += 256){
        int g = i / 72, c = i % 72;
        bufX[XIDX(g, 0, c)] = 0; bufX[XIDX(g, 13, c)] = 0;
        bufY[XIDX(g, 0, c)] = 0; bufY[XIDX(g, 13, c)] = 0;
    }
    // stage z -> bufX rows 1..12
    for (int i = tid; i < 384; i += 256){
        int g = i / 96, r = i % 96, t = r >> 3, ch = r & 7;
        *(s16v8*)&bufX[XIDX(g, 1 + t, ch * 8)] =
            *(const s16v8*)(z + (size_t)(n0 + g) * 768 + t * 64 + ch * 8);
    }
    __syncthreads();

    // ---- mix MFMA: y = relu(z*W + b) ----
    {
        f32v4 accm[3];
#pragma unroll
        for (int mt = 0; mt < 3; mt++) accm[mt] = (f32v4)0.f;
#pragma unroll
        for (int mt = 0; mt < 3; mt++){
            int m = mt * 16 + col;
            int g = m / 12, t = m - 12 * g;
#pragma unroll
            for (int ks = 0; ks < 2; ks++){
                s16v8 a = *(const s16v8*)&bufX[XIDX(g, 1 + t, ks * 32 + quad * 8)];
                accm[mt] = __builtin_amdgcn_mfma_f32_16x16x32_bf16(a, Bm[ks], accm[mt], 0, 0, 0);
            }
        }
#pragma unroll
        for (int mt = 0; mt < 3; mt++){
#pragma unroll
            for (int r = 0; r < 4; r++){
                int m2 = mt * 16 + quad * 4 + r;
                int g = m2 / 12, t = m2 - 12 * g;
                bufY[XIDX(g, 1 + t, o_mix)] = f2bf(fmaxf(accm[mt][r] + bmv, 0.f));
            }
        }
    }
    __syncthreads();

    // ---- gated conv 1: bufY -> bufX ----
    {
        f32v4 aP[3], aQ[3];
#pragma unroll
        for (int mt = 0; mt < 3; mt++){ aP[mt] = (f32v4)0.f; aQ[mt] = (f32v4)0.f; }
#pragma unroll
        for (int mt = 0; mt < 3; mt++){
            int m = mt * 16 + col;
            int g = m / 12, t = m - 12 * g;
#pragma unroll
            for (int d = 0; d < 3; d++)
#pragma unroll
                for (int ks = 0; ks < 2; ks++){
                    s16v8 a = *(const s16v8*)&bufY[XIDX(g, t + d, ks * 32 + quad * 8)];
                    aP[mt] = __builtin_amdgcn_mfma_f32_16x16x32_bf16(a, Bf1[d][ks][0], aP[mt], 0, 0, 0);
                    aQ[mt] = __builtin_amdgcn_mfma_f32_16x16x32_bf16(a, Bf1[d][ks][1], aQ[mt], 0, 0, 0);
                }
        }
#pragma unroll
        for (int mt = 0; mt < 3; mt++){
#pragma unroll
            for (int r = 0; r < 4; r++){
                int m2 = mt * 16 + quad * 4 + r;
                int g = m2 / 12, t = m2 - 12 * g;
                float pv = aP[mt][r] + b1P, qv = aQ[mt][r] + b1Q;
                u16 hv = f2bf(pv / (1.f + __expf(-qv)));
                if (LAST) bufX[g * 1008 + o_p * 12 + t] = hv;   // H2[g][c*12+t]
                else      bufX[XIDX(g, 1 + t, o_p)] = hv;
            }
        }
    }
    __syncthreads();

    if (!LAST){
        // ---- gated conv 2: bufX -> bufY -> outMid ----
        f32v4 aP[3], aQ[3];
#pragma unroll
        for (int mt = 0; mt < 3; mt++){ aP[mt] = (f32v4)0.f; aQ[mt] = (f32v4)0.f; }
#pragma unroll
        for (int mt = 0; mt < 3; mt++){
            int m = mt * 16 + col;
            int g = m / 12, t = m - 12 * g;
#pragma unroll
            for (int d = 0; d < 3; d++)
#pragma unroll
                for (int ks = 0; ks < 2; ks++){
                    s16v8 a = *(const s16v8*)&bufX[XIDX(g, t + d, ks * 32 + quad * 8)];
                    aP[mt] = __builtin_amdgcn_mfma_f32_16x16x32_bf16(a, Bf2[d][ks][0], aP[mt], 0, 0, 0);
                    aQ[mt] = __builtin_amdgcn_mfma_f32_16x16x32_bf16(a, Bf2[d][ks][1], aQ[mt], 0, 0, 0);
                }
        }
#pragma unroll
        for (int mt = 0; mt < 3; mt++){
#pragma unroll
            for (int r = 0; r < 4; r++){
                int m2 = mt * 16 + quad * 4 + r;
                int g = m2 / 12, t = m2 - 12 * g;
                float pv = aP[mt][r] + b2P, qv = aQ[mt][r] + b2Q;
                bufY[XIDX(g, 1 + t, o_p)] = f2bf(pv / (1.f + __expf(-qv)));
            }
        }
        __syncthreads();
        for (int i = tid; i < 384; i += 256){
            int g = i / 96, r = i % 96, t = r / 8, ch = r % 8;
            *(s16v8*)(outMid + (size_t)(n0 + g) * 768 + t * 64 + ch * 8) =
                *(const s16v8*)&bufY[XIDX(g, 1 + t, ch * 8)];
        }
    } else {
        // ---- final: out[g][o] = sum_k H2[g][k]*fw[o][k] + fb[o] (wave 0) ----
        if (wave == 0){
            f32v4 accF = {0.f, 0.f, 0.f, 0.f};
            int g4 = col & 3;
#pragma unroll
            for (int ks = 0; ks < 24; ks++){
                s16v8 a = *(const s16v8*)&bufX[g4 * 1008 + ks * 32 + quad * 8];
                s16v8 bfr = {0, 0, 0, 0, 0, 0, 0, 0};
                if (col < 12)
                    bfr = *(const s16v8*)(fw + (size_t)col * 768 + ks * 32 + quad * 8);
                accF = __builtin_amdgcn_mfma_f32_16x16x32_bf16(a, bfr, accF, 0, 0, 0);
            }
            if (col < 12 && quad == 0){
                float bb = bf2f(fb[col]);
#pragma unroll
                for (int r = 0; r < 4; r++){
                    outFin[(size_t)(n0 + r) * 12 + col] = accF[r] + bb;
                }
            }
        }
    }
}

// ---------------- launch ----------------
static inline size_t align256(size_t x){ return (x + 255) & ~(size_t)255; }

extern "C" void kernel_launch(void* const* d_in, const int* in_sizes, int n_in,
                              void* d_out, int out_size, void* d_ws, size_t ws_size,
                              hipStream_t stream){
    const float* x  = (const float*)d_in[0];
    const int* ei   = (const int*)d_in[1];
    const float* ew = (const float*)d_in[2];

    char* w = (char*)d_ws;
    u16* bufA    = (u16*)w;  w += align256((size_t)N_NODES * 768 * sizeof(u16));
    u16* bufB    = (u16*)w;  w += align256((size_t)N_NODES * 768 * sizeof(u16));
    u16* zA      = (u16*)w;  w += align256((size_t)N_NODES * 768 * sizeof(u16));
    u16* zB      = (u16*)w;  w += align256((size_t)N_NODES * 768 * sizeof(u16));
    float* deg   = (float*)w; w += align256(N_NODES * sizeof(float));
    int* cur     = (int*)w;   w += align256(N_NODES * sizeof(int));
    int2* epack  = (int2*)w;  w += align256((size_t)N_NODES * BUCKET * sizeof(int2));
    u16* cvt     = (u16*)w;   w += align256(104076 * sizeof(u16));

    u16* tc1a_w = cvt + 0;        // [d][128][32]
    u16* tc1a_b = cvt + 12288;
    u16* gc1_w  = cvt + 12416;
    u16* gc1_b  = cvt + 16512;
    u16* tc1b_w = cvt + 16576;    // [d][128][64]
    u16* tc1b_b = cvt + 41152;
    u16* tc2a_w = cvt + 41280;    // [d][128][64]
    u16* tc2a_b = cvt + 65856;
    u16* gc2_w  = cvt + 65984;
    u16* gc2_b  = cvt + 70080;
    u16* tc2b_w = cvt + 70144;    // [d][128][64]
    u16* tc2b_b = cvt + 94720;
    u16* fin_w  = cvt + 94848;
    u16* fin_b  = cvt + 104064;

    SmallPtrs ps;
    ps.p[0]  = d_in[3];  ps.p[1]  = d_in[4];
    ps.p[2]  = d_in[5];  ps.p[3]  = d_in[6];
    ps.p[4]  = d_in[7];  ps.p[5]  = d_in[8];
    ps.p[6]  = d_in[9];  ps.p[7]  = d_in[10];
    ps.p[8]  = d_in[11]; ps.p[9]  = d_in[12];
    ps.p[10] = d_in[13]; ps.p[11] = d_in[14];
    ps.p[12] = d_in[15]; ps.p[13] = d_in[16];

    k_convert_init<<<(104076 + 255) / 256, 256, 0, stream>>>(ps, cvt, deg, cur);
    k_gconv_count<<<1250 + 625, 256, 0, stream>>>(x, tc1a_w, tc1a_b, bufA, ei, ew, deg);
    k_scatter<<<625, 256, 0, stream>>>(ei, ew, deg, cur, epack);

    k_gather<<<313 * 8, 256, 0, stream>>>(bufA, deg, cur, epack, zA);
    k_fused<false><<<2500, 256, 0, stream>>>(zA, gc1_w, gc1_b, tc1b_w, tc1b_b,
                                             tc2a_w, tc2a_b, nullptr, nullptr,
                                             bufB, nullptr);
    k_gather<<<313 * 8, 256, 0, stream>>>(bufB, deg, cur, epack, zB);
    k_fused<true><<<2500, 256, 0, stream>>>(zB, gc2_w, gc2_b, tc2b_w, tc2b_b,
                                            nullptr, nullptr, fin_w, fin_b,
                                            nullptr, (float*)d_out);
}

// Round 10
// 246.594 us; speedup vs baseline: 1.0821x; 1.0608x over previous
//
#include <hip/hip_runtime.h>
#include <hip/hip_bf16.h>
#include <stdint.h>

#define N_NODES 10000
#define N_EDGES 160000
#define BUCKET 128

typedef unsigned short u16;
typedef unsigned int u32;
typedef short s16v8 __attribute__((ext_vector_type(8)));
typedef float f32v4 __attribute__((ext_vector_type(4)));

__device__ __forceinline__ float bf2f(u16 v){ return __uint_as_float(((u32)v) << 16); }
__device__ __forceinline__ u16 f2bf(float f){
    u32 u = __float_as_uint(f);
    u32 r = (u + 0x7fffu + ((u >> 16) & 1u)) >> 16;
    return (u16)r;
}

// ---------------- weights fp32->bf16 (+tconv transpose to [d][o][c]) + graph init ----------------
struct SmallPtrs { const void* p[14]; };

__device__ __constant__ const int g_seg_off[15] = {
    0, 12288, 12416, 16512, 16576, 41152, 41280,
    65856, 65984, 70080, 70144, 94720, 94848, 104064, 104076
};
// 0=straight, 1=tconv CIN=32 transpose, 2=tconv CIN=64 transpose
__device__ __constant__ const int g_seg_kind[14] = {
    1, 0, 0, 0, 2, 0, 2, 0, 0, 0, 2, 0, 0, 0
};

__global__ void k_convert_init(SmallPtrs ps, u16* __restrict__ dst,
                               float* deg, int* cur){
    int i = blockIdx.x * blockDim.x + threadIdx.x;
    if (i < 104076){
        int seg = 0, base = 0;
#pragma unroll
        for (int s = 0; s < 14; s++){
            if (i >= g_seg_off[s]){ seg = s; base = g_seg_off[s]; }
        }
        int li = i - base;
        float v = ((const float*)ps.p[seg])[li];
        int kind = g_seg_kind[seg];
        int dsto = li;
        if (kind){
            int CIN = (kind == 1) ? 32 : 64;
            int o = li / (3 * CIN);
            int rem = li - o * (3 * CIN);
            int c = rem / 3, d = rem - c * 3;
            dsto = d * 128 * CIN + o * CIN + c;     // [d][o][c]
        }
        dst[base + dsto] = f2bf(v);
    }
    if (i < N_NODES){ deg[i] = 1.0f; cur[i] = 0; }
}

// ---------------- merged: gconv32 (blocks 0..1249) || deg + bucket-scatter (1250..1874) ----------------
__launch_bounds__(256, 2)
__global__ void k_gconv_count(const float* __restrict__ xin, const u16* __restrict__ wg,
                              const u16* __restrict__ bg, u16* __restrict__ out,
                              const int* __restrict__ ei, const float* __restrict__ ew,
                              float* deg, int* cur, int2* __restrict__ epack){
    if (blockIdx.x >= 1250){
        int e = (blockIdx.x - 1250) * 256 + threadIdx.x;
        if (e < N_EDGES){
            int s = ei[e];
            int d = ei[N_EDGES + e];
            float wv = ew[e];
            atomicAdd(&deg[d], wv);
            int p = atomicAdd(&cur[d], 1);
            if (p < BUCKET) epack[d * BUCKET + p] = make_int2(s, __float_as_int(wv));
        }
        return;
    }
    __shared__ __attribute__((aligned(16))) u16 xT[8][14][40];
    __shared__ __attribute__((aligned(16))) u16 Ho[8][12][72];
    int tid = threadIdx.x;
    int n0 = blockIdx.x * 8;

    int lane = tid & 63, wave = tid >> 6;
    int col = lane & 15, quad = lane >> 4;
    int o_p = wave * 16 + col, o_q = o_p + 64;

    s16v8 Bf[3][2];
#pragma unroll
    for (int pq = 0; pq < 2; pq++){
        int o = pq ? o_q : o_p;
#pragma unroll
        for (int d = 0; d < 3; d++)
            Bf[d][pq] = *(const s16v8*)(wg + d * 4096 + o * 32 + quad * 8);
    }

    for (int i = tid; i < 8 * 40; i += 256){
        int g = i / 40, c = i % 40;
        xT[g][0][c] = 0; xT[g][13][c] = 0;
    }
    {
        int g = tid >> 5, c = tid & 31;
        const float4* p = (const float4*)(xin + ((size_t)(n0 + g) * 32 + c) * 12);
        float4 v0 = p[0], v1 = p[1], v2 = p[2];
        xT[g][1][c] = f2bf(v0.x);  xT[g][2][c] = f2bf(v0.y);
        xT[g][3][c] = f2bf(v0.z);  xT[g][4][c] = f2bf(v0.w);
        xT[g][5][c] = f2bf(v1.x);  xT[g][6][c] = f2bf(v1.y);
        xT[g][7][c] = f2bf(v1.z);  xT[g][8][c] = f2bf(v1.w);
        xT[g][9][c] = f2bf(v2.x);  xT[g][10][c] = f2bf(v2.y);
        xT[g][11][c] = f2bf(v2.z); xT[g][12][c] = f2bf(v2.w);
    }
    __syncthreads();

    f32v4 aP[6], aQ[6];
#pragma unroll
    for (int mt = 0; mt < 6; mt++){ aP[mt] = (f32v4)0.f; aQ[mt] = (f32v4)0.f; }
#pragma unroll
    for (int mt = 0; mt < 6; mt++){
        int m = mt * 16 + col;
        int g = m / 12, t = m - 12 * g;
#pragma unroll
        for (int d = 0; d < 3; d++){
            s16v8 a = *(const s16v8*)&xT[g][t + d][quad * 8];
            aP[mt] = __builtin_amdgcn_mfma_f32_16x16x32_bf16(a, Bf[d][0], aP[mt], 0, 0, 0);
            aQ[mt] = __builtin_amdgcn_mfma_f32_16x16x32_bf16(a, Bf[d][1], aQ[mt], 0, 0, 0);
        }
    }
    float bP = bf2f(bg[o_p]), bQ = bf2f(bg[o_q]);
#pragma unroll
    for (int mt = 0; mt < 6; mt++){
#pragma unroll
        for (int r = 0; r < 4; r++){
            int m2 = mt * 16 + quad * 4 + r;
            int g = m2 / 12, t = m2 - 12 * g;
            float pv = aP[mt][r] + bP, qv = aQ[mt][r] + bQ;
            Ho[g][t][o_p] = f2bf(pv / (1.f + __expf(-qv)));
        }
    }
    __syncthreads();
    for (int i = tid; i < 768; i += 256){
        int g = i / 96, r = i % 96, t = r / 8, ch = r % 8;
        *(s16v8*)(out + (size_t)(n0 + g) * 768 + t * 64 + ch * 8) = *(const s16v8*)&Ho[g][t][ch * 8];
    }
}

// ---------------- slice-partitioned GCN gather (norm computed on the fly from deg) ----------------
// slice = blockIdx % 8 (XCD round-robin): per-XCD feature slice ~1.9 MB -> L2-resident.
__launch_bounds__(256, 6)
__global__ void k_gather(const u16* __restrict__ src, const float* __restrict__ deg,
                         const int* __restrict__ cur, const int2* __restrict__ ep,
                         u16* __restrict__ z){
    int slice = blockIdx.x & 7;
    int nb = blockIdx.x >> 3;
    int nl = threadIdx.x >> 3;
    int l8 = threadIdx.x & 7;
    int n = nb * 32 + nl;
    if (n >= N_NODES) return;
    int base = slice * 96 + l8 * 12;
    const u16* xr = src + (size_t)n * 768 + base;
    float dn = rsqrtf(deg[n]);
    float sw = dn * dn;
    float acc[12];
#pragma unroll
    for (int k = 0; k < 3; k++){
        ushort4 v = *(const ushort4*)(xr + k * 4);
        acc[k * 4 + 0] = sw * bf2f(v.x); acc[k * 4 + 1] = sw * bf2f(v.y);
        acc[k * 4 + 2] = sw * bf2f(v.z); acc[k * 4 + 3] = sw * bf2f(v.w);
    }
    int e = cur[n]; if (e > BUCKET) e = BUCKET;
    const int2* eb = ep + (size_t)n * BUCKET;
    int p = 0;
    for (; p + 1 < e; p += 2){
        int2 e0 = eb[p], e1 = eb[p + 1];
        float w0 = dn * __int_as_float(e0.y) * rsqrtf(deg[e0.x]);
        float w1 = dn * __int_as_float(e1.y) * rsqrtf(deg[e1.x]);
        const u16* q0 = src + (size_t)e0.x * 768 + base;
        const u16* q1 = src + (size_t)e1.x * 768 + base;
        ushort4 a0 = *(const ushort4*)(q0);
        ushort4 a1 = *(const ushort4*)(q0 + 4);
        ushort4 a2 = *(const ushort4*)(q0 + 8);
        ushort4 c0 = *(const ushort4*)(q1);
        ushort4 c1 = *(const ushort4*)(q1 + 4);
        ushort4 c2 = *(const ushort4*)(q1 + 8);
        acc[0] = fmaf(w0, bf2f(a0.x), acc[0]); acc[1] = fmaf(w0, bf2f(a0.y), acc[1]);
        acc[2] = fmaf(w0, bf2f(a0.z), acc[2]); acc[3] = fmaf(w0, bf2f(a0.w), acc[3]);
        acc[4] = fmaf(w0, bf2f(a1.x), acc[4]); acc[5] = fmaf(w0, bf2f(a1.y), acc[5]);
        acc[6] = fmaf(w0, bf2f(a1.z), acc[6]); acc[7] = fmaf(w0, bf2f(a1.w), acc[7]);
        acc[8] = fmaf(w0, bf2f(a2.x), acc[8]); acc[9] = fmaf(w0, bf2f(a2.y), acc[9]);
        acc[10] = fmaf(w0, bf2f(a2.z), acc[10]); acc[11] = fmaf(w0, bf2f(a2.w), acc[11]);
        acc[0] = fmaf(w1, bf2f(c0.x), acc[0]); acc[1] = fmaf(w1, bf2f(c0.y), acc[1]);
        acc[2] = fmaf(w1, bf2f(c0.z), acc[2]); acc[3] = fmaf(w1, bf2f(c0.w), acc[3]);
        acc[4] = fmaf(w1, bf2f(c1.x), acc[4]); acc[5] = fmaf(w1, bf2f(c1.y), acc[5]);
        acc[6] = fmaf(w1, bf2f(c1.z), acc[6]); acc[7] = fmaf(w1, bf2f(c1.w), acc[7]);
        acc[8] = fmaf(w1, bf2f(c2.x), acc[8]); acc[9] = fmaf(w1, bf2f(c2.y), acc[9]);
        acc[10] = fmaf(w1, bf2f(c2.z), acc[10]); acc[11] = fmaf(w1, bf2f(c2.w), acc[11]);
    }
    if (p < e){
        int2 e0 = eb[p];
        float w0 = dn * __int_as_float(e0.y) * rsqrtf(deg[e0.x]);
        const u16* q0 = src + (size_t)e0.x * 768 + base;
#pragma unroll
        for (int k = 0; k < 3; k++){
            ushort4 v = *(const ushort4*)(q0 + k * 4);
            acc[k * 4 + 0] = fmaf(w0, bf2f(v.x), acc[k * 4 + 0]);
            acc[k * 4 + 1] = fmaf(w0, bf2f(v.y), acc[k * 4 + 1]);
            acc[k * 4 + 2] = fmaf(w0, bf2f(v.z), acc[k * 4 + 2]);
            acc[k * 4 + 3] = fmaf(w0, bf2f(v.w), acc[k * 4 + 3]);
        }
    }
    u16* zo = z + (size_t)n * 768 + base;
#pragma unroll
    for (int k = 0; k < 3; k++){
        ushort4 hv;
        hv.x = f2bf(acc[k * 4 + 0]); hv.y = f2bf(acc[k * 4 + 1]);
        hv.z = f2bf(acc[k * 4 + 2]); hv.w = f2bf(acc[k * 4 + 3]);
        *(ushort4*)(zo + k * 4) = hv;
    }
}

// ---------------- fused: stage z -> mix(relu) -> gconv w1 -> (MID: gconv w2 | LAST: final) ----------------
// 8 nodes/block; B-frags loaded per phase with ks-outer loop (24 VGPR live, no spills).
#define XIDX(g, row, c) (((g) * 14 + (row)) * 72 + (c))

template<bool LAST>
__launch_bounds__(256, 4)
__global__ void k_fused(const u16* __restrict__ z,      // [n][t*64+c] bf16 (pre-aggregated)
                        const u16* __restrict__ Wmix, const u16* __restrict__ bmix,
                        const u16* __restrict__ w1, const u16* __restrict__ b1,
                        const u16* __restrict__ w2, const u16* __restrict__ b2,
                        const u16* __restrict__ fw, const u16* __restrict__ fb,
                        u16* __restrict__ outMid, float* __restrict__ outFin){
    __shared__ __attribute__((aligned(16))) u16 bufX[8 * 14 * 72];
    __shared__ __attribute__((aligned(16))) u16 bufY[8 * 14 * 72];
    int tid = threadIdx.x;
    int n0 = blockIdx.x * 8;
    int lane = tid & 63, wave = tid >> 6;
    int col = lane & 15, quad = lane >> 4;
    int o_p = wave * 16 + col, o_q = o_p + 64;

    // zero time-pad rows
    for (int i = tid; i < 8 * 72; i += 256){
        int g = i / 72, c = i % 72;
        bufX[XIDX(g, 0, c)] = 0; bufX[XIDX(g, 13, c)] = 0;
        bufY[XIDX(g, 0, c)] = 0; bufY[XIDX(g, 13, c)] = 0;
    }
    // stage z -> bufX rows 1..12
    for (int i = tid; i < 768; i += 256){
        int g = i / 96, r = i % 96, t = r >> 3, ch = r & 7;
        *(s16v8*)&bufX[XIDX(g, 1 + t, ch * 8)] =
            *(const s16v8*)(z + (size_t)(n0 + g) * 768 + t * 64 + ch * 8);
    }
    __syncthreads();

    // ---- mix MFMA: y = relu(z*W + b), 6 m-tiles ----
    {
        f32v4 accm[6];
#pragma unroll
        for (int mt = 0; mt < 6; mt++) accm[mt] = (f32v4)0.f;
#pragma unroll
        for (int ks = 0; ks < 2; ks++){
            s16v8 Bm = *(const s16v8*)(Wmix + (size_t)o_p * 64 + ks * 32 + quad * 8);
#pragma unroll
            for (int mt = 0; mt < 6; mt++){
                int m = mt * 16 + col;
                int g = m / 12, t = m - 12 * g;
                s16v8 a = *(const s16v8*)&bufX[XIDX(g, 1 + t, ks * 32 + quad * 8)];
                accm[mt] = __builtin_amdgcn_mfma_f32_16x16x32_bf16(a, Bm, accm[mt], 0, 0, 0);
            }
        }
        float bm = bf2f(bmix[o_p]);
#pragma unroll
        for (int mt = 0; mt < 6; mt++){
#pragma unroll
            for (int r = 0; r < 4; r++){
                int m2 = mt * 16 + quad * 4 + r;
                int g = m2 / 12, t = m2 - 12 * g;
                bufY[XIDX(g, 1 + t, o_p)] = f2bf(fmaxf(accm[mt][r] + bm, 0.f));
            }
        }
    }
    __syncthreads();

    // ---- gated conv 1: bufY -> bufX ----
    {
        f32v4 aP[6], aQ[6];
#pragma unroll
        for (int mt = 0; mt < 6; mt++){ aP[mt] = (f32v4)0.f; aQ[mt] = (f32v4)0.f; }
#pragma unroll
        for (int ks = 0; ks < 2; ks++){
            s16v8 Bf[3][2];
#pragma unroll
            for (int pq = 0; pq < 2; pq++){
                int o = pq ? o_q : o_p;
#pragma unroll
                for (int d = 0; d < 3; d++)
                    Bf[d][pq] = *(const s16v8*)(w1 + d * 8192 + o * 64 + ks * 32 + quad * 8);
            }
#pragma unroll
            for (int mt = 0; mt < 6; mt++){
                int m = mt * 16 + col;
                int g = m / 12, t = m - 12 * g;
#pragma unroll
                for (int d = 0; d < 3; d++){
                    s16v8 a = *(const s16v8*)&bufY[XIDX(g, t + d, ks * 32 + quad * 8)];
                    aP[mt] = __builtin_amdgcn_mfma_f32_16x16x32_bf16(a, Bf[d][0], aP[mt], 0, 0, 0);
                    aQ[mt] = __builtin_amdgcn_mfma_f32_16x16x32_bf16(a, Bf[d][1], aQ[mt], 0, 0, 0);
                }
            }
        }
        float bP = bf2f(b1[o_p]), bQ = bf2f(b1[o_q]);
#pragma unroll
        for (int mt = 0; mt < 6; mt++){
#pragma unroll
            for (int r = 0; r < 4; r++){
                int m2 = mt * 16 + quad * 4 + r;
                int g = m2 / 12, t = m2 - 12 * g;
                float pv = aP[mt][r] + bP, qv = aQ[mt][r] + bQ;
                u16 hv = f2bf(pv / (1.f + __expf(-qv)));
                if (LAST) bufX[g * 1008 + o_p * 12 + t] = hv;   // H2[g][c*12+t]
                else      bufX[XIDX(g, 1 + t, o_p)] = hv;
            }
        }
    }
    __syncthreads();

    if (!LAST){
        // ---- gated conv 2: bufX -> bufY -> outMid ----
        f32v4 aP[6], aQ[6];
#pragma unroll
        for (int mt = 0; mt < 6; mt++){ aP[mt] = (f32v4)0.f; aQ[mt] = (f32v4)0.f; }
#pragma unroll
        for (int ks = 0; ks < 2; ks++){
            s16v8 Bf[3][2];
#pragma unroll
            for (int pq = 0; pq < 2; pq++){
                int o = pq ? o_q : o_p;
#pragma unroll
                for (int d = 0; d < 3; d++)
                    Bf[d][pq] = *(const s16v8*)(w2 + d * 8192 + o * 64 + ks * 32 + quad * 8);
            }
#pragma unroll
            for (int mt = 0; mt < 6; mt++){
                int m = mt * 16 + col;
                int g = m / 12, t = m - 12 * g;
#pragma unroll
                for (int d = 0; d < 3; d++){
                    s16v8 a = *(const s16v8*)&bufX[XIDX(g, t + d, ks * 32 + quad * 8)];
                    aP[mt] = __builtin_amdgcn_mfma_f32_16x16x32_bf16(a, Bf[d][0], aP[mt], 0, 0, 0);
                    aQ[mt] = __builtin_amdgcn_mfma_f32_16x16x32_bf16(a, Bf[d][1], aQ[mt], 0, 0, 0);
                }
            }
        }
        float bP = bf2f(b2[o_p]), bQ = bf2f(b2[o_q]);
#pragma unroll
        for (int mt = 0; mt < 6; mt++){
#pragma unroll
            for (int r = 0; r < 4; r++){
                int m2 = mt * 16 + quad * 4 + r;
                int g = m2 / 12, t = m2 - 12 * g;
                float pv = aP[mt][r] + bP, qv = aQ[mt][r] + bQ;
                bufY[XIDX(g, 1 + t, o_p)] = f2bf(pv / (1.f + __expf(-qv)));
            }
        }
        __syncthreads();
        for (int i = tid; i < 768; i += 256){
            int g = i / 96, r = i % 96, t = r / 8, ch = r % 8;
            *(s16v8*)(outMid + (size_t)(n0 + g) * 768 + t * 64 + ch * 8) =
                *(const s16v8*)&bufY[XIDX(g, 1 + t, ch * 8)];
        }
    } else {
        // ---- final: out[g][o] = sum_k H2[g][k]*fw[o][k] + fb[o] (wave 0; 8 nodes in rows 0..7) ----
        if (wave == 0){
            f32v4 accF = {0.f, 0.f, 0.f, 0.f};
            int g8 = col & 7;
#pragma unroll
            for (int ks = 0; ks < 24; ks++){
                s16v8 a = *(const s16v8*)&bufX[g8 * 1008 + ks * 32 + quad * 8];
                s16v8 bfr = {0, 0, 0, 0, 0, 0, 0, 0};
                if (col < 12)
                    bfr = *(const s16v8*)(fw + (size_t)col * 768 + ks * 32 + quad * 8);
                accF = __builtin_amdgcn_mfma_f32_16x16x32_bf16(a, bfr, accF, 0, 0, 0);
            }
            if (col < 12 && quad < 2){
                float bb = bf2f(fb[col]);
#pragma unroll
                for (int r = 0; r < 4; r++){
                    int g = quad * 4 + r;
                    outFin[(size_t)(n0 + g) * 12 + col] = accF[r] + bb;
                }
            }
        }
    }
}

// ---------------- launch ----------------
static inline size_t align256(size_t x){ return (x + 255) & ~(size_t)255; }

extern "C" void kernel_launch(void* const* d_in, const int* in_sizes, int n_in,
                              void* d_out, int out_size, void* d_ws, size_t ws_size,
                              hipStream_t stream){
    const float* x  = (const float*)d_in[0];
    const int* ei   = (const int*)d_in[1];
    const float* ew = (const float*)d_in[2];

    char* w = (char*)d_ws;
    u16* bufA    = (u16*)w;  w += align256((size_t)N_NODES * 768 * sizeof(u16));
    u16* bufB    = (u16*)w;  w += align256((size_t)N_NODES * 768 * sizeof(u16));
    u16* zA      = (u16*)w;  w += align256((size_t)N_NODES * 768 * sizeof(u16));
    u16* zB      = (u16*)w;  w += align256((size_t)N_NODES * 768 * sizeof(u16));
    float* deg   = (float*)w; w += align256(N_NODES * sizeof(float));
    int* cur     = (int*)w;   w += align256(N_NODES * sizeof(int));
    int2* epack  = (int2*)w;  w += align256((size_t)N_NODES * BUCKET * sizeof(int2));
    u16* cvt     = (u16*)w;   w += align256(104076 * sizeof(u16));

    u16* tc1a_w = cvt + 0;        // [d][128][32]
    u16* tc1a_b = cvt + 12288;
    u16* gc1_w  = cvt + 12416;
    u16* gc1_b  = cvt + 16512;
    u16* tc1b_w = cvt + 16576;    // [d][128][64]
    u16* tc1b_b = cvt + 41152;
    u16* tc2a_w = cvt + 41280;    // [d][128][64]
    u16* tc2a_b = cvt + 65856;
    u16* gc2_w  = cvt + 65984;
    u16* gc2_b  = cvt + 70080;
    u16* tc2b_w = cvt + 70144;    // [d][128][64]
    u16* tc2b_b = cvt + 94720;
    u16* fin_w  = cvt + 94848;
    u16* fin_b  = cvt + 104064;

    SmallPtrs ps;
    ps.p[0]  = d_in[3];  ps.p[1]  = d_in[4];
    ps.p[2]  = d_in[5];  ps.p[3]  = d_in[6];
    ps.p[4]  = d_in[7];  ps.p[5]  = d_in[8];
    ps.p[6]  = d_in[9];  ps.p[7]  = d_in[10];
    ps.p[8]  = d_in[11]; ps.p[9]  = d_in[12];
    ps.p[10] = d_in[13]; ps.p[11] = d_in[14];
    ps.p[12] = d_in[15]; ps.p[13] = d_in[16];

    k_convert_init<<<(104076 + 255) / 256, 256, 0, stream>>>(ps, cvt, deg, cur);
    k_gconv_count<<<1250 + 625, 256, 0, stream>>>(x, tc1a_w, tc1a_b, bufA, ei, ew, deg, cur, epack);

    k_gather<<<313 * 8, 256, 0, stream>>>(bufA, deg, cur, epack, zA);
    k_fused<false><<<1250, 256, 0, stream>>>(zA, gc1_w, gc1_b, tc1b_w, tc1b_b,
                                             tc2a_w, tc2a_b, nullptr, nullptr,
                                             bufB, nullptr);
    k_gather<<<313 * 8, 256, 0, stream>>>(bufB, deg, cur, epack, zB);
    k_fused<true><<<1250, 256, 0, stream>>>(zB, gc2_w, gc2_b, tc2b_w, tc2b_b,
                                            nullptr, nullptr, fin_w, fin_b,
                                            nullptr, (float*)d_out);
}

// Round 11
// 241.095 us; speedup vs baseline: 1.1068x; 1.0228x over previous
//
#include <hip/hip_runtime.h>
#include <hip/hip_bf16.h>
#include <stdint.h>

#define N_NODES 10000
#define N_EDGES 160000
#define BUCKET 128

typedef unsigned short u16;
typedef unsigned int u32;
typedef short s16v8 __attribute__((ext_vector_type(8)));
typedef float f32v4 __attribute__((ext_vector_type(4)));

__device__ __forceinline__ float bf2f(u16 v){ return __uint_as_float(((u32)v) << 16); }
__device__ __forceinline__ u16 f2bf(float f){
    u32 u = __float_as_uint(f);
    u32 r = (u + 0x7fffu + ((u >> 16) & 1u)) >> 16;
    return (u16)r;
}

// ---------------- weights fp32->bf16 (+tconv transpose to [d][o][c]) + graph init ----------------
struct SmallPtrs { const void* p[14]; };

__device__ __constant__ const int g_seg_off[15] = {
    0, 12288, 12416, 16512, 16576, 41152, 41280,
    65856, 65984, 70080, 70144, 94720, 94848, 104064, 104076
};
// 0=straight, 1=tconv CIN=32 transpose, 2=tconv CIN=64 transpose
__device__ __constant__ const int g_seg_kind[14] = {
    1, 0, 0, 0, 2, 0, 2, 0, 0, 0, 2, 0, 0, 0
};

__global__ void k_convert_init(SmallPtrs ps, u16* __restrict__ dst,
                               float* deg, int* cur){
    int i = blockIdx.x * blockDim.x + threadIdx.x;
    if (i < 104076){
        int seg = 0, base = 0;
#pragma unroll
        for (int s = 0; s < 14; s++){
            if (i >= g_seg_off[s]){ seg = s; base = g_seg_off[s]; }
        }
        int li = i - base;
        float v = ((const float*)ps.p[seg])[li];
        int kind = g_seg_kind[seg];
        int dsto = li;
        if (kind){
            int CIN = (kind == 1) ? 32 : 64;
            int o = li / (3 * CIN);
            int rem = li - o * (3 * CIN);
            int c = rem / 3, d = rem - c * 3;
            dsto = d * 128 * CIN + o * CIN + c;     // [d][o][c]
        }
        dst[base + dsto] = f2bf(v);
    }
    if (i < N_NODES){ deg[i] = 1.0f; cur[i] = 0; }
}

// ---------------- merged: gconv32 (blocks 0..1249) || deg + bucket-scatter (1250..1874) ----------------
__launch_bounds__(256, 2)
__global__ void k_gconv_count(const float* __restrict__ xin, const u16* __restrict__ wg,
                              const u16* __restrict__ bg, u16* __restrict__ out,
                              const int* __restrict__ ei, const float* __restrict__ ew,
                              float* deg, int* cur, int2* __restrict__ epack){
    if (blockIdx.x >= 1250){
        int e = (blockIdx.x - 1250) * 256 + threadIdx.x;
        if (e < N_EDGES){
            int s = ei[e];
            int d = ei[N_EDGES + e];
            float wv = ew[e];
            atomicAdd(&deg[d], wv);
            int p = atomicAdd(&cur[d], 1);
            if (p < BUCKET) epack[d * BUCKET + p] = make_int2(s, __float_as_int(wv));
        }
        return;
    }
    __shared__ __attribute__((aligned(16))) u16 xT[8][14][40];
    __shared__ __attribute__((aligned(16))) u16 Ho[8][12][72];
    int tid = threadIdx.x;
    int n0 = blockIdx.x * 8;

    int lane = tid & 63, wave = tid >> 6;
    int col = lane & 15, quad = lane >> 4;
    int o_p = wave * 16 + col, o_q = o_p + 64;

    s16v8 Bf[3][2];
#pragma unroll
    for (int pq = 0; pq < 2; pq++){
        int o = pq ? o_q : o_p;
#pragma unroll
        for (int d = 0; d < 3; d++)
            Bf[d][pq] = *(const s16v8*)(wg + d * 4096 + o * 32 + quad * 8);
    }

    for (int i = tid; i < 8 * 40; i += 256){
        int g = i / 40, c = i % 40;
        xT[g][0][c] = 0; xT[g][13][c] = 0;
    }
    {
        int g = tid >> 5, c = tid & 31;
        const float4* p = (const float4*)(xin + ((size_t)(n0 + g) * 32 + c) * 12);
        float4 v0 = p[0], v1 = p[1], v2 = p[2];
        xT[g][1][c] = f2bf(v0.x);  xT[g][2][c] = f2bf(v0.y);
        xT[g][3][c] = f2bf(v0.z);  xT[g][4][c] = f2bf(v0.w);
        xT[g][5][c] = f2bf(v1.x);  xT[g][6][c] = f2bf(v1.y);
        xT[g][7][c] = f2bf(v1.z);  xT[g][8][c] = f2bf(v1.w);
        xT[g][9][c] = f2bf(v2.x);  xT[g][10][c] = f2bf(v2.y);
        xT[g][11][c] = f2bf(v2.z); xT[g][12][c] = f2bf(v2.w);
    }
    __syncthreads();

    f32v4 aP[6], aQ[6];
#pragma unroll
    for (int mt = 0; mt < 6; mt++){ aP[mt] = (f32v4)0.f; aQ[mt] = (f32v4)0.f; }
#pragma unroll
    for (int mt = 0; mt < 6; mt++){
        int m = mt * 16 + col;
        int g = m / 12, t = m - 12 * g;
#pragma unroll
        for (int d = 0; d < 3; d++){
            s16v8 a = *(const s16v8*)&xT[g][t + d][quad * 8];
            aP[mt] = __builtin_amdgcn_mfma_f32_16x16x32_bf16(a, Bf[d][0], aP[mt], 0, 0, 0);
            aQ[mt] = __builtin_amdgcn_mfma_f32_16x16x32_bf16(a, Bf[d][1], aQ[mt], 0, 0, 0);
        }
    }
    float bP = bf2f(bg[o_p]), bQ = bf2f(bg[o_q]);
#pragma unroll
    for (int mt = 0; mt < 6; mt++){
#pragma unroll
        for (int r = 0; r < 4; r++){
            int m2 = mt * 16 + quad * 4 + r;
            int g = m2 / 12, t = m2 - 12 * g;
            float pv = aP[mt][r] + bP, qv = aQ[mt][r] + bQ;
            Ho[g][t][o_p] = f2bf(pv / (1.f + __expf(-qv)));
        }
    }
    __syncthreads();
    for (int i = tid; i < 768; i += 256){
        int g = i / 96, r = i % 96, t = r / 8, ch = r % 8;
        *(s16v8*)(out + (size_t)(n0 + g) * 768 + t * 64 + ch * 8) = *(const s16v8*)&Ho[g][t][ch * 8];
    }
}

// ---------------- slice-partitioned, edge-parallel GCN gather ----------------
// slice = blockIdx % 8 (XCD round-robin, per-XCD slice ~1.9 MB L2-resident).
// 8 nodes/block, 32 lanes/node: eg = edge group (4-way edge parallel, 2-unrolled),
// l8 = feature chunk (12 elems). Partials reduced via shfl_xor(8),(16).
__launch_bounds__(256, 4)
__global__ void k_gather(const u16* __restrict__ src, const float* __restrict__ deg,
                         const int* __restrict__ cur, const int2* __restrict__ ep,
                         u16* __restrict__ z){
    int slice = blockIdx.x & 7;
    int nb = blockIdx.x >> 3;            // 0..1249
    int tid = threadIdx.x;
    int nl = tid >> 5;                   // node within block (0..7)
    int sub = tid & 31;
    int eg = sub >> 3;                   // edge group 0..3
    int l8 = sub & 7;                    // chunk 0..7
    int n = nb * 8 + nl;
    int base = slice * 96 + l8 * 12;
    float dn = rsqrtf(deg[n]);

    float acc[12];
    if (eg == 0){
        float sw = dn * dn;
        const u16* xr = src + (size_t)n * 768 + base;
#pragma unroll
        for (int k = 0; k < 3; k++){
            ushort4 v = *(const ushort4*)(xr + k * 4);
            acc[k * 4 + 0] = sw * bf2f(v.x); acc[k * 4 + 1] = sw * bf2f(v.y);
            acc[k * 4 + 2] = sw * bf2f(v.z); acc[k * 4 + 3] = sw * bf2f(v.w);
        }
    } else {
#pragma unroll
        for (int k = 0; k < 12; k++) acc[k] = 0.f;
    }

    int e = cur[n]; if (e > BUCKET) e = BUCKET;
    const int2* eb = ep + (size_t)n * BUCKET;
    int p = eg;
    for (; p + 4 < e; p += 8){
        int2 e0 = eb[p], e1 = eb[p + 4];
        float w0 = dn * __int_as_float(e0.y) * rsqrtf(deg[e0.x]);
        float w1 = dn * __int_as_float(e1.y) * rsqrtf(deg[e1.x]);
        const u16* q0 = src + (size_t)e0.x * 768 + base;
        const u16* q1 = src + (size_t)e1.x * 768 + base;
        ushort4 a0 = *(const ushort4*)(q0);
        ushort4 a1 = *(const ushort4*)(q0 + 4);
        ushort4 a2 = *(const ushort4*)(q0 + 8);
        ushort4 c0 = *(const ushort4*)(q1);
        ushort4 c1 = *(const ushort4*)(q1 + 4);
        ushort4 c2 = *(const ushort4*)(q1 + 8);
        acc[0] = fmaf(w0, bf2f(a0.x), acc[0]); acc[1] = fmaf(w0, bf2f(a0.y), acc[1]);
        acc[2] = fmaf(w0, bf2f(a0.z), acc[2]); acc[3] = fmaf(w0, bf2f(a0.w), acc[3]);
        acc[4] = fmaf(w0, bf2f(a1.x), acc[4]); acc[5] = fmaf(w0, bf2f(a1.y), acc[5]);
        acc[6] = fmaf(w0, bf2f(a1.z), acc[6]); acc[7] = fmaf(w0, bf2f(a1.w), acc[7]);
        acc[8] = fmaf(w0, bf2f(a2.x), acc[8]); acc[9] = fmaf(w0, bf2f(a2.y), acc[9]);
        acc[10] = fmaf(w0, bf2f(a2.z), acc[10]); acc[11] = fmaf(w0, bf2f(a2.w), acc[11]);
        acc[0] = fmaf(w1, bf2f(c0.x), acc[0]); acc[1] = fmaf(w1, bf2f(c0.y), acc[1]);
        acc[2] = fmaf(w1, bf2f(c0.z), acc[2]); acc[3] = fmaf(w1, bf2f(c0.w), acc[3]);
        acc[4] = fmaf(w1, bf2f(c1.x), acc[4]); acc[5] = fmaf(w1, bf2f(c1.y), acc[5]);
        acc[6] = fmaf(w1, bf2f(c1.z), acc[6]); acc[7] = fmaf(w1, bf2f(c1.w), acc[7]);
        acc[8] = fmaf(w1, bf2f(c2.x), acc[8]); acc[9] = fmaf(w1, bf2f(c2.y), acc[9]);
        acc[10] = fmaf(w1, bf2f(c2.z), acc[10]); acc[11] = fmaf(w1, bf2f(c2.w), acc[11]);
    }
    if (p < e){
        int2 e0 = eb[p];
        float w0 = dn * __int_as_float(e0.y) * rsqrtf(deg[e0.x]);
        const u16* q0 = src + (size_t)e0.x * 768 + base;
#pragma unroll
        for (int k = 0; k < 3; k++){
            ushort4 v = *(const ushort4*)(q0 + k * 4);
            acc[k * 4 + 0] = fmaf(w0, bf2f(v.x), acc[k * 4 + 0]);
            acc[k * 4 + 1] = fmaf(w0, bf2f(v.y), acc[k * 4 + 1]);
            acc[k * 4 + 2] = fmaf(w0, bf2f(v.z), acc[k * 4 + 2]);
            acc[k * 4 + 3] = fmaf(w0, bf2f(v.w), acc[k * 4 + 3]);
        }
    }
    // reduce edge-group partials (lanes differ in bits 3,4 — stays within each node's 32 lanes)
#pragma unroll
    for (int k = 0; k < 12; k++){
        acc[k] += __shfl_xor(acc[k], 8, 64);
        acc[k] += __shfl_xor(acc[k], 16, 64);
    }
    if (eg == 0){
        u16* zo = z + (size_t)n * 768 + base;
#pragma unroll
        for (int k = 0; k < 3; k++){
            ushort4 hv;
            hv.x = f2bf(acc[k * 4 + 0]); hv.y = f2bf(acc[k * 4 + 1]);
            hv.z = f2bf(acc[k * 4 + 2]); hv.w = f2bf(acc[k * 4 + 3]);
            *(ushort4*)(zo + k * 4) = hv;
        }
    }
}

// ---------------- fused: stage z -> mix(relu) -> gconv w1 -> (MID: gconv w2 | LAST: final) ----------------
// 8 nodes/block; B-frags loaded per phase with ks-outer loop (24 VGPR live, no spills).
#define XIDX(g, row, c) (((g) * 14 + (row)) * 72 + (c))

template<bool LAST>
__launch_bounds__(256, 4)
__global__ void k_fused(const u16* __restrict__ z,      // [n][t*64+c] bf16 (pre-aggregated)
                        const u16* __restrict__ Wmix, const u16* __restrict__ bmix,
                        const u16* __restrict__ w1, const u16* __restrict__ b1,
                        const u16* __restrict__ w2, const u16* __restrict__ b2,
                        const u16* __restrict__ fw, const u16* __restrict__ fb,
                        u16* __restrict__ outMid, float* __restrict__ outFin){
    __shared__ __attribute__((aligned(16))) u16 bufX[8 * 14 * 72];
    __shared__ __attribute__((aligned(16))) u16 bufY[8 * 14 * 72];
    int tid = threadIdx.x;
    int n0 = blockIdx.x * 8;
    int lane = tid & 63, wave = tid >> 6;
    int col = lane & 15, quad = lane >> 4;
    int o_p = wave * 16 + col, o_q = o_p + 64;

    // zero time-pad rows
    for (int i = tid; i < 8 * 72; i += 256){
        int g = i / 72, c = i % 72;
        bufX[XIDX(g, 0, c)] = 0; bufX[XIDX(g, 13, c)] = 0;
        bufY[XIDX(g, 0, c)] = 0; bufY[XIDX(g, 13, c)] = 0;
    }
    // stage z -> bufX rows 1..12
    for (int i = tid; i < 768; i += 256){
        int g = i / 96, r = i % 96, t = r >> 3, ch = r & 7;
        *(s16v8*)&bufX[XIDX(g, 1 + t, ch * 8)] =
            *(const s16v8*)(z + (size_t)(n0 + g) * 768 + t * 64 + ch * 8);
    }
    __syncthreads();

    // ---- mix MFMA: y = relu(z*W + b), 6 m-tiles ----
    {
        f32v4 accm[6];
#pragma unroll
        for (int mt = 0; mt < 6; mt++) accm[mt] = (f32v4)0.f;
#pragma unroll
        for (int ks = 0; ks < 2; ks++){
            s16v8 Bm = *(const s16v8*)(Wmix + (size_t)o_p * 64 + ks * 32 + quad * 8);
#pragma unroll
            for (int mt = 0; mt < 6; mt++){
                int m = mt * 16 + col;
                int g = m / 12, t = m - 12 * g;
                s16v8 a = *(const s16v8*)&bufX[XIDX(g, 1 + t, ks * 32 + quad * 8)];
                accm[mt] = __builtin_amdgcn_mfma_f32_16x16x32_bf16(a, Bm, accm[mt], 0, 0, 0);
            }
        }
        float bm = bf2f(bmix[o_p]);
#pragma unroll
        for (int mt = 0; mt < 6; mt++){
#pragma unroll
            for (int r = 0; r < 4; r++){
                int m2 = mt * 16 + quad * 4 + r;
                int g = m2 / 12, t = m2 - 12 * g;
                bufY[XIDX(g, 1 + t, o_p)] = f2bf(fmaxf(accm[mt][r] + bm, 0.f));
            }
        }
    }
    __syncthreads();

    // ---- gated conv 1: bufY -> bufX ----
    {
        f32v4 aP[6], aQ[6];
#pragma unroll
        for (int mt = 0; mt < 6; mt++){ aP[mt] = (f32v4)0.f; aQ[mt] = (f32v4)0.f; }
#pragma unroll
        for (int ks = 0; ks < 2; ks++){
            s16v8 Bf[3][2];
#pragma unroll
            for (int pq = 0; pq < 2; pq++){
                int o = pq ? o_q : o_p;
#pragma unroll
                for (int d = 0; d < 3; d++)
                    Bf[d][pq] = *(const s16v8*)(w1 + d * 8192 + o * 64 + ks * 32 + quad * 8);
            }
#pragma unroll
            for (int mt = 0; mt < 6; mt++){
                int m = mt * 16 + col;
                int g = m / 12, t = m - 12 * g;
#pragma unroll
                for (int d = 0; d < 3; d++){
                    s16v8 a = *(const s16v8*)&bufY[XIDX(g, t + d, ks * 32 + quad * 8)];
                    aP[mt] = __builtin_amdgcn_mfma_f32_16x16x32_bf16(a, Bf[d][0], aP[mt], 0, 0, 0);
                    aQ[mt] = __builtin_amdgcn_mfma_f32_16x16x32_bf16(a, Bf[d][1], aQ[mt], 0, 0, 0);
                }
            }
        }
        float bP = bf2f(b1[o_p]), bQ = bf2f(b1[o_q]);
#pragma unroll
        for (int mt = 0; mt < 6; mt++){
#pragma unroll
            for (int r = 0; r < 4; r++){
                int m2 = mt * 16 + quad * 4 + r;
                int g = m2 / 12, t = m2 - 12 * g;
                float pv = aP[mt][r] + bP, qv = aQ[mt][r] + bQ;
                u16 hv = f2bf(pv / (1.f + __expf(-qv)));
                if (LAST) bufX[g * 1008 + o_p * 12 + t] = hv;   // H2[g][c*12+t]
                else      bufX[XIDX(g, 1 + t, o_p)] = hv;
            }
        }
    }
    __syncthreads();

    if (!LAST){
        // ---- gated conv 2: bufX -> bufY -> outMid ----
        f32v4 aP[6], aQ[6];
#pragma unroll
        for (int mt = 0; mt < 6; mt++){ aP[mt] = (f32v4)0.f; aQ[mt] = (f32v4)0.f; }
#pragma unroll
        for (int ks = 0; ks < 2; ks++){
            s16v8 Bf[3][2];
#pragma unroll
            for (int pq = 0; pq < 2; pq++){
                int o = pq ? o_q : o_p;
#pragma unroll
                for (int d = 0; d < 3; d++)
                    Bf[d][pq] = *(const s16v8*)(w2 + d * 8192 + o * 64 + ks * 32 + quad * 8);
            }
#pragma unroll
            for (int mt = 0; mt < 6; mt++){
                int m = mt * 16 + col;
                int g = m / 12, t = m - 12 * g;
#pragma unroll
                for (int d = 0; d < 3; d++){
                    s16v8 a = *(const s16v8*)&bufX[XIDX(g, t + d, ks * 32 + quad * 8)];
                    aP[mt] = __builtin_amdgcn_mfma_f32_16x16x32_bf16(a, Bf[d][0], aP[mt], 0, 0, 0);
                    aQ[mt] = __builtin_amdgcn_mfma_f32_16x16x32_bf16(a, Bf[d][1], aQ[mt], 0, 0, 0);
                }
            }
        }
        float bP = bf2f(b2[o_p]), bQ = bf2f(b2[o_q]);
#pragma unroll
        for (int mt = 0; mt < 6; mt++){
#pragma unroll
            for (int r = 0; r < 4; r++){
                int m2 = mt * 16 + quad * 4 + r;
                int g = m2 / 12, t = m2 - 12 * g;
                float pv = aP[mt][r] + bP, qv = aQ[mt][r] + bQ;
                bufY[XIDX(g, 1 + t, o_p)] = f2bf(pv / (1.f + __expf(-qv)));
            }
        }
        __syncthreads();
        for (int i = tid; i < 768; i += 256){
            int g = i / 96, r = i % 96, t = r / 8, ch = r % 8;
            *(s16v8*)(outMid + (size_t)(n0 + g) * 768 + t * 64 + ch * 8) =
                *(const s16v8*)&bufY[XIDX(g, 1 + t, ch * 8)];
        }
    } else {
        // ---- final: out[g][o] = sum_k H2[g][k]*fw[o][k] + fb[o] (wave 0; 8 nodes in rows 0..7) ----
        if (wave == 0){
            f32v4 accF = {0.f, 0.f, 0.f, 0.f};
            int g8 = col & 7;
#pragma unroll
            for (int ks = 0; ks < 24; ks++){
                s16v8 a = *(const s16v8*)&bufX[g8 * 1008 + ks * 32 + quad * 8];
                s16v8 bfr = {0, 0, 0, 0, 0, 0, 0, 0};
                if (col < 12)
                    bfr = *(const s16v8*)(fw + (size_t)col * 768 + ks * 32 + quad * 8);
                accF = __builtin_amdgcn_mfma_f32_16x16x32_bf16(a, bfr, accF, 0, 0, 0);
            }
            if (col < 12 && quad < 2){
                float bb = bf2f(fb[col]);
#pragma unroll
                for (int r = 0; r < 4; r++){
                    int g = quad * 4 + r;
                    outFin[(size_t)(n0 + g) * 12 + col] = accF[r] + bb;
                }
            }
        }
    }
}

// ---------------- launch ----------------
static inline size_t align256(size_t x){ return (x + 255) & ~(size_t)255; }

extern "C" void kernel_launch(void* const* d_in, const int* in_sizes, int n_in,
                              void* d_out, int out_size, void* d_ws, size_t ws_size,
                              hipStream_t stream){
    const float* x  = (const float*)d_in[0];
    const int* ei   = (const int*)d_in[1];
    const float* ew = (const float*)d_in[2];

    char* w = (char*)d_ws;
    u16* bufA    = (u16*)w;  w += align256((size_t)N_NODES * 768 * sizeof(u16));
    u16* bufB    = (u16*)w;  w += align256((size_t)N_NODES * 768 * sizeof(u16));
    u16* zA      = (u16*)w;  w += align256((size_t)N_NODES * 768 * sizeof(u16));
    u16* zB      = (u16*)w;  w += align256((size_t)N_NODES * 768 * sizeof(u16));
    float* deg   = (float*)w; w += align256(N_NODES * sizeof(float));
    int* cur     = (int*)w;   w += align256(N_NODES * sizeof(int));
    int2* epack  = (int2*)w;  w += align256((size_t)N_NODES * BUCKET * sizeof(int2));
    u16* cvt     = (u16*)w;   w += align256(104076 * sizeof(u16));

    u16* tc1a_w = cvt + 0;        // [d][128][32]
    u16* tc1a_b = cvt + 12288;
    u16* gc1_w  = cvt + 12416;
    u16* gc1_b  = cvt + 16512;
    u16* tc1b_w = cvt + 16576;    // [d][128][64]
    u16* tc1b_b = cvt + 41152;
    u16* tc2a_w = cvt + 41280;    // [d][128][64]
    u16* tc2a_b = cvt + 65856;
    u16* gc2_w  = cvt + 65984;
    u16* gc2_b  = cvt + 70080;
    u16* tc2b_w = cvt + 70144;    // [d][128][64]
    u16* tc2b_b = cvt + 94720;
    u16* fin_w  = cvt + 94848;
    u16* fin_b  = cvt + 104064;

    SmallPtrs ps;
    ps.p[0]  = d_in[3];  ps.p[1]  = d_in[4];
    ps.p[2]  = d_in[5];  ps.p[3]  = d_in[6];
    ps.p[4]  = d_in[7];  ps.p[5]  = d_in[8];
    ps.p[6]  = d_in[9];  ps.p[7]  = d_in[10];
    ps.p[8]  = d_in[11]; ps.p[9]  = d_in[12];
    ps.p[10] = d_in[13]; ps.p[11] = d_in[14];
    ps.p[12] = d_in[15]; ps.p[13] = d_in[16];

    k_convert_init<<<(104076 + 255) / 256, 256, 0, stream>>>(ps, cvt, deg, cur);
    k_gconv_count<<<1250 + 625, 256, 0, stream>>>(x, tc1a_w, tc1a_b, bufA, ei, ew, deg, cur, epack);

    k_gather<<<1250 * 8, 256, 0, stream>>>(bufA, deg, cur, epack, zA);
    k_fused<false><<<1250, 256, 0, stream>>>(zA, gc1_w, gc1_b, tc1b_w, tc1b_b,
                                             tc2a_w, tc2a_b, nullptr, nullptr,
                                             bufB, nullptr);
    k_gather<<<1250 * 8, 256, 0, stream>>>(bufB, deg, cur, epack, zB);
    k_fused<true><<<1250, 256, 0, stream>>>(zB, gc2_w, gc2_b, tc2b_w, tc2b_b,
                                            nullptr, nullptr, fin_w, fin_b,
                                            nullptr, (float*)d_out);
}

// Round 12
// 232.109 us; speedup vs baseline: 1.1497x; 1.0387x over previous
//
#include <hip/hip_runtime.h>
#include <hip/hip_bf16.h>
#include <stdint.h>

#define N_NODES 10000
#define N_EDGES 160000
#define BUCKET 128

typedef unsigned short u16;
typedef unsigned int u32;
typedef short s16v8 __attribute__((ext_vector_type(8)));
typedef float f32v4 __attribute__((ext_vector_type(4)));

__device__ __forceinline__ float bf2f(u16 v){ return __uint_as_float(((u32)v) << 16); }
__device__ __forceinline__ u16 f2bf(float f){
    u32 u = __float_as_uint(f);
    u32 r = (u + 0x7fffu + ((u >> 16) & 1u)) >> 16;
    return (u16)r;
}

// ---------------- weights fp32->bf16 (+tconv transpose to [d][o][c]) + graph init ----------------
struct SmallPtrs { const void* p[14]; };

__device__ __constant__ const int g_seg_off[15] = {
    0, 12288, 12416, 16512, 16576, 41152, 41280,
    65856, 65984, 70080, 70144, 94720, 94848, 104064, 104076
};
// 0=straight, 1=tconv CIN=32 transpose, 2=tconv CIN=64 transpose
__device__ __constant__ const int g_seg_kind[14] = {
    1, 0, 0, 0, 2, 0, 2, 0, 0, 0, 2, 0, 0, 0
};

__global__ void k_convert_init(SmallPtrs ps, u16* __restrict__ dst,
                               float* deg, int* cur){
    int i = blockIdx.x * blockDim.x + threadIdx.x;
    if (i < 104076){
        int seg = 0, base = 0;
#pragma unroll
        for (int s = 0; s < 14; s++){
            if (i >= g_seg_off[s]){ seg = s; base = g_seg_off[s]; }
        }
        int li = i - base;
        float v = ((const float*)ps.p[seg])[li];
        int kind = g_seg_kind[seg];
        int dsto = li;
        if (kind){
            int CIN = (kind == 1) ? 32 : 64;
            int o = li / (3 * CIN);
            int rem = li - o * (3 * CIN);
            int c = rem / 3, d = rem - c * 3;
            dsto = d * 128 * CIN + o * CIN + c;     // [d][o][c]
        }
        dst[base + dsto] = f2bf(v);
    }
    if (i < N_NODES){ deg[i] = 1.0f; cur[i] = 0; }
}

// ---------------- merged: gconv32 (blocks 0..1249) || deg + bucket-scatter (1250..1874) ----------------
// LDS union: xT [8][14][40] (8960 B) overlaid with Ho [8][12][72] (13824 B) -> 13.8 KB total.
__launch_bounds__(256, 4)
__global__ void k_gconv_count(const float* __restrict__ xin, const u16* __restrict__ wg,
                              const u16* __restrict__ bg, u16* __restrict__ out,
                              const int* __restrict__ ei, const float* __restrict__ ew,
                              float* deg, int* cur, int2* __restrict__ epack){
    if (blockIdx.x >= 1250){
        int e = (blockIdx.x - 1250) * 256 + threadIdx.x;
        if (e < N_EDGES){
            int s = ei[e];
            int d = ei[N_EDGES + e];
            float wv = ew[e];
            atomicAdd(&deg[d], wv);
            int p = atomicAdd(&cur[d], 1);
            if (p < BUCKET) epack[d * BUCKET + p] = make_int2(s, __float_as_int(wv));
        }
        return;
    }
    __shared__ __attribute__((aligned(16))) u16 shbuf[6912];   // 13824 B union
    u16* xT = shbuf;    // [g][row][c] = g*560 + row*40 + c  (rows 0..13, c 0..39)
    u16* Ho = shbuf;    // [g][t][o]   = g*864 + t*72 + o    (after MFMA, overwrites xT)
    int tid = threadIdx.x;
    int n0 = blockIdx.x * 8;

    int lane = tid & 63, wave = tid >> 6;
    int col = lane & 15, quad = lane >> 4;
    int o_p = wave * 16 + col, o_q = o_p + 64;

    s16v8 Bf[3][2];
#pragma unroll
    for (int pq = 0; pq < 2; pq++){
        int o = pq ? o_q : o_p;
#pragma unroll
        for (int d = 0; d < 3; d++)
            Bf[d][pq] = *(const s16v8*)(wg + d * 4096 + o * 32 + quad * 8);
    }

    for (int i = tid; i < 8 * 40; i += 256){
        int g = i / 40, c = i % 40;
        xT[g * 560 + 0 * 40 + c] = 0; xT[g * 560 + 13 * 40 + c] = 0;
    }
    {
        int g = tid >> 5, c = tid & 31;
        const float4* p = (const float4*)(xin + ((size_t)(n0 + g) * 32 + c) * 12);
        float4 v0 = p[0], v1 = p[1], v2 = p[2];
        u16* xb = xT + g * 560 + c;
        xb[1 * 40] = f2bf(v0.x);  xb[2 * 40] = f2bf(v0.y);
        xb[3 * 40] = f2bf(v0.z);  xb[4 * 40] = f2bf(v0.w);
        xb[5 * 40] = f2bf(v1.x);  xb[6 * 40] = f2bf(v1.y);
        xb[7 * 40] = f2bf(v1.z);  xb[8 * 40] = f2bf(v1.w);
        xb[9 * 40] = f2bf(v2.x);  xb[10 * 40] = f2bf(v2.y);
        xb[11 * 40] = f2bf(v2.z); xb[12 * 40] = f2bf(v2.w);
    }
    __syncthreads();

    f32v4 aP[6], aQ[6];
#pragma unroll
    for (int mt = 0; mt < 6; mt++){ aP[mt] = (f32v4)0.f; aQ[mt] = (f32v4)0.f; }
#pragma unroll
    for (int mt = 0; mt < 6; mt++){
        int m = mt * 16 + col;
        int g = m / 12, t = m - 12 * g;
#pragma unroll
        for (int d = 0; d < 3; d++){
            s16v8 a = *(const s16v8*)&xT[g * 560 + (t + d) * 40 + quad * 8];
            aP[mt] = __builtin_amdgcn_mfma_f32_16x16x32_bf16(a, Bf[d][0], aP[mt], 0, 0, 0);
            aQ[mt] = __builtin_amdgcn_mfma_f32_16x16x32_bf16(a, Bf[d][1], aQ[mt], 0, 0, 0);
        }
    }
    __syncthreads();   // all xT reads done before Ho overwrites the union buffer
    float bP = bf2f(bg[o_p]), bQ = bf2f(bg[o_q]);
#pragma unroll
    for (int mt = 0; mt < 6; mt++){
#pragma unroll
        for (int r = 0; r < 4; r++){
            int m2 = mt * 16 + quad * 4 + r;
            int g = m2 / 12, t = m2 - 12 * g;
            float pv = aP[mt][r] + bP, qv = aQ[mt][r] + bQ;
            Ho[g * 864 + t * 72 + o_p] = f2bf(pv / (1.f + __expf(-qv)));
        }
    }
    __syncthreads();
    for (int i = tid; i < 768; i += 256){
        int g = i / 96, r = i % 96, t = r / 8, ch = r % 8;
        *(s16v8*)(out + (size_t)(n0 + g) * 768 + t * 64 + ch * 8) =
            *(const s16v8*)&Ho[g * 864 + t * 72 + ch * 8];
    }
}

// ---------------- epack normalization (once; both gathers reuse) ----------------
__global__ void k_norm(const float* __restrict__ deg, const int* __restrict__ cur,
                       int2* __restrict__ ep){
    int i = blockIdx.x * blockDim.x + threadIdx.x;
    int n = i >> 7, slot = i & 127;
    if (n >= N_NODES) return;
    int cnt = cur[n]; if (cnt > BUCKET) cnt = BUCKET;
    if (slot < cnt){
        int2 e = ep[(size_t)n * BUCKET + slot];
        float w = __int_as_float(e.y) * rsqrtf(deg[e.x]) * rsqrtf(deg[n]);
        ep[(size_t)n * BUCKET + slot].y = __float_as_int(w);
    }
}

// ---------------- slice-partitioned, edge-parallel GCN gather (pre-normalized weights) ----------------
// slice = blockIdx % 8 (XCD round-robin, per-XCD slice ~1.9 MB L2-resident).
// 8 nodes/block, 32 lanes/node: eg = edge group (4-way edge parallel, 2-unrolled),
// l8 = feature chunk (12 elems). Partials reduced via shfl_xor(8),(16).
__launch_bounds__(256, 4)
__global__ void k_gather(const u16* __restrict__ src, const float* __restrict__ deg,
                         const int* __restrict__ cur, const int2* __restrict__ ep,
                         u16* __restrict__ z){
    int slice = blockIdx.x & 7;
    int nb = blockIdx.x >> 3;            // 0..1249
    int tid = threadIdx.x;
    int nl = tid >> 5;                   // node within block (0..7)
    int sub = tid & 31;
    int eg = sub >> 3;                   // edge group 0..3
    int l8 = sub & 7;                    // chunk 0..7
    int n = nb * 8 + nl;
    int base = slice * 96 + l8 * 12;

    float acc[12];
    if (eg == 0){
        float sw = 1.0f / deg[n];        // self-loop: dis[n]*1*dis[n]
        const u16* xr = src + (size_t)n * 768 + base;
#pragma unroll
        for (int k = 0; k < 3; k++){
            ushort4 v = *(const ushort4*)(xr + k * 4);
            acc[k * 4 + 0] = sw * bf2f(v.x); acc[k * 4 + 1] = sw * bf2f(v.y);
            acc[k * 4 + 2] = sw * bf2f(v.z); acc[k * 4 + 3] = sw * bf2f(v.w);
        }
    } else {
#pragma unroll
        for (int k = 0; k < 12; k++) acc[k] = 0.f;
    }

    int e = cur[n]; if (e > BUCKET) e = BUCKET;
    const int2* eb = ep + (size_t)n * BUCKET;
    int p = eg;
    for (; p + 4 < e; p += 8){
        int2 e0 = eb[p], e1 = eb[p + 4];
        float w0 = __int_as_float(e0.y), w1 = __int_as_float(e1.y);
        const u16* q0 = src + (size_t)e0.x * 768 + base;
        const u16* q1 = src + (size_t)e1.x * 768 + base;
        ushort4 a0 = *(const ushort4*)(q0);
        ushort4 a1 = *(const ushort4*)(q0 + 4);
        ushort4 a2 = *(const ushort4*)(q0 + 8);
        ushort4 c0 = *(const ushort4*)(q1);
        ushort4 c1 = *(const ushort4*)(q1 + 4);
        ushort4 c2 = *(const ushort4*)(q1 + 8);
        acc[0] = fmaf(w0, bf2f(a0.x), acc[0]); acc[1] = fmaf(w0, bf2f(a0.y), acc[1]);
        acc[2] = fmaf(w0, bf2f(a0.z), acc[2]); acc[3] = fmaf(w0, bf2f(a0.w), acc[3]);
        acc[4] = fmaf(w0, bf2f(a1.x), acc[4]); acc[5] = fmaf(w0, bf2f(a1.y), acc[5]);
        acc[6] = fmaf(w0, bf2f(a1.z), acc[6]); acc[7] = fmaf(w0, bf2f(a1.w), acc[7]);
        acc[8] = fmaf(w0, bf2f(a2.x), acc[8]); acc[9] = fmaf(w0, bf2f(a2.y), acc[9]);
        acc[10] = fmaf(w0, bf2f(a2.z), acc[10]); acc[11] = fmaf(w0, bf2f(a2.w), acc[11]);
        acc[0] = fmaf(w1, bf2f(c0.x), acc[0]); acc[1] = fmaf(w1, bf2f(c0.y), acc[1]);
        acc[2] = fmaf(w1, bf2f(c0.z), acc[2]); acc[3] = fmaf(w1, bf2f(c0.w), acc[3]);
        acc[4] = fmaf(w1, bf2f(c1.x), acc[4]); acc[5] = fmaf(w1, bf2f(c1.y), acc[5]);
        acc[6] = fmaf(w1, bf2f(c1.z), acc[6]); acc[7] = fmaf(w1, bf2f(c1.w), acc[7]);
        acc[8] = fmaf(w1, bf2f(c2.x), acc[8]); acc[9] = fmaf(w1, bf2f(c2.y), acc[9]);
        acc[10] = fmaf(w1, bf2f(c2.z), acc[10]); acc[11] = fmaf(w1, bf2f(c2.w), acc[11]);
    }
    if (p < e){
        int2 e0 = eb[p];
        float w0 = __int_as_float(e0.y);
        const u16* q0 = src + (size_t)e0.x * 768 + base;
#pragma unroll
        for (int k = 0; k < 3; k++){
            ushort4 v = *(const ushort4*)(q0 + k * 4);
            acc[k * 4 + 0] = fmaf(w0, bf2f(v.x), acc[k * 4 + 0]);
            acc[k * 4 + 1] = fmaf(w0, bf2f(v.y), acc[k * 4 + 1]);
            acc[k * 4 + 2] = fmaf(w0, bf2f(v.z), acc[k * 4 + 2]);
            acc[k * 4 + 3] = fmaf(w0, bf2f(v.w), acc[k * 4 + 3]);
        }
    }
    // reduce edge-group partials (lanes differ in bits 3,4 — stays within each node's 32 lanes)
#pragma unroll
    for (int k = 0; k < 12; k++){
        acc[k] += __shfl_xor(acc[k], 8, 64);
        acc[k] += __shfl_xor(acc[k], 16, 64);
    }
    if (eg == 0){
        u16* zo = z + (size_t)n * 768 + base;
#pragma unroll
        for (int k = 0; k < 3; k++){
            ushort4 hv;
            hv.x = f2bf(acc[k * 4 + 0]); hv.y = f2bf(acc[k * 4 + 1]);
            hv.z = f2bf(acc[k * 4 + 2]); hv.w = f2bf(acc[k * 4 + 3]);
            *(ushort4*)(zo + k * 4) = hv;
        }
    }
}

// ---------------- fused: stage z -> mix(relu) -> gconv w1 -> (MID: gconv w2 | LAST: final) ----------------
// 8 nodes/block; B-frags loaded per phase with ks-outer loop (24 VGPR live, no spills).
#define XIDX(g, row, c) (((g) * 14 + (row)) * 72 + (c))

template<bool LAST>
__launch_bounds__(256, 4)
__global__ void k_fused(const u16* __restrict__ z,      // [n][t*64+c] bf16 (pre-aggregated)
                        const u16* __restrict__ Wmix, const u16* __restrict__ bmix,
                        const u16* __restrict__ w1, const u16* __restrict__ b1,
                        const u16* __restrict__ w2, const u16* __restrict__ b2,
                        const u16* __restrict__ fw, const u16* __restrict__ fb,
                        u16* __restrict__ outMid, float* __restrict__ outFin){
    __shared__ __attribute__((aligned(16))) u16 bufX[8 * 14 * 72];
    __shared__ __attribute__((aligned(16))) u16 bufY[8 * 14 * 72];
    int tid = threadIdx.x;
    int n0 = blockIdx.x * 8;
    int lane = tid & 63, wave = tid >> 6;
    int col = lane & 15, quad = lane >> 4;
    int o_p = wave * 16 + col, o_q = o_p + 64;

    // zero time-pad rows
    for (int i = tid; i < 8 * 72; i += 256){
        int g = i / 72, c = i % 72;
        bufX[XIDX(g, 0, c)] = 0; bufX[XIDX(g, 13, c)] = 0;
        bufY[XIDX(g, 0, c)] = 0; bufY[XIDX(g, 13, c)] = 0;
    }
    // stage z -> bufX rows 1..12
    for (int i = tid; i < 768; i += 256){
        int g = i / 96, r = i % 96, t = r >> 3, ch = r & 7;
        *(s16v8*)&bufX[XIDX(g, 1 + t, ch * 8)] =
            *(const s16v8*)(z + (size_t)(n0 + g) * 768 + t * 64 + ch * 8);
    }
    __syncthreads();

    // ---- mix MFMA: y = relu(z*W + b), 6 m-tiles ----
    {
        f32v4 accm[6];
#pragma unroll
        for (int mt = 0; mt < 6; mt++) accm[mt] = (f32v4)0.f;
#pragma unroll
        for (int ks = 0; ks < 2; ks++){
            s16v8 Bm = *(const s16v8*)(Wmix + (size_t)o_p * 64 + ks * 32 + quad * 8);
#pragma unroll
            for (int mt = 0; mt < 6; mt++){
                int m = mt * 16 + col;
                int g = m / 12, t = m - 12 * g;
                s16v8 a = *(const s16v8*)&bufX[XIDX(g, 1 + t, ks * 32 + quad * 8)];
                accm[mt] = __builtin_amdgcn_mfma_f32_16x16x32_bf16(a, Bm, accm[mt], 0, 0, 0);
            }
        }
        float bm = bf2f(bmix[o_p]);
#pragma unroll
        for (int mt = 0; mt < 6; mt++){
#pragma unroll
            for (int r = 0; r < 4; r++){
                int m2 = mt * 16 + quad * 4 + r;
                int g = m2 / 12, t = m2 - 12 * g;
                bufY[XIDX(g, 1 + t, o_p)] = f2bf(fmaxf(accm[mt][r] + bm, 0.f));
            }
        }
    }
    __syncthreads();

    // ---- gated conv 1: bufY -> bufX ----
    {
        f32v4 aP[6], aQ[6];
#pragma unroll
        for (int mt = 0; mt < 6; mt++){ aP[mt] = (f32v4)0.f; aQ[mt] = (f32v4)0.f; }
#pragma unroll
        for (int ks = 0; ks < 2; ks++){
            s16v8 Bf[3][2];
#pragma unroll
            for (int pq = 0; pq < 2; pq++){
                int o = pq ? o_q : o_p;
#pragma unroll
                for (int d = 0; d < 3; d++)
                    Bf[d][pq] = *(const s16v8*)(w1 + d * 8192 + o * 64 + ks * 32 + quad * 8);
            }
#pragma unroll
            for (int mt = 0; mt < 6; mt++){
                int m = mt * 16 + col;
                int g = m / 12, t = m - 12 * g;
#pragma unroll
                for (int d = 0; d < 3; d++){
                    s16v8 a = *(const s16v8*)&bufY[XIDX(g, t + d, ks * 32 + quad * 8)];
                    aP[mt] = __builtin_amdgcn_mfma_f32_16x16x32_bf16(a, Bf[d][0], aP[mt], 0, 0, 0);
                    aQ[mt] = __builtin_amdgcn_mfma_f32_16x16x32_bf16(a, Bf[d][1], aQ[mt], 0, 0, 0);
                }
            }
        }
        float bP = bf2f(b1[o_p]), bQ = bf2f(b1[o_q]);
#pragma unroll
        for (int mt = 0; mt < 6; mt++){
#pragma unroll
            for (int r = 0; r < 4; r++){
                int m2 = mt * 16 + quad * 4 + r;
                int g = m2 / 12, t = m2 - 12 * g;
                float pv = aP[mt][r] + bP, qv = aQ[mt][r] + bQ;
                u16 hv = f2bf(pv / (1.f + __expf(-qv)));
                if (LAST) bufX[g * 1008 + o_p * 12 + t] = hv;   // H2[g][c*12+t]
                else      bufX[XIDX(g, 1 + t, o_p)] = hv;
            }
        }
    }
    __syncthreads();

    if (!LAST){
        // ---- gated conv 2: bufX -> bufY -> outMid ----
        f32v4 aP[6], aQ[6];
#pragma unroll
        for (int mt = 0; mt < 6; mt++){ aP[mt] = (f32v4)0.f; aQ[mt] = (f32v4)0.f; }
#pragma unroll
        for (int ks = 0; ks < 2; ks++){
            s16v8 Bf[3][2];
#pragma unroll
            for (int pq = 0; pq < 2; pq++){
                int o = pq ? o_q : o_p;
#pragma unroll
                for (int d = 0; d < 3; d++)
                    Bf[d][pq] = *(const s16v8*)(w2 + d * 8192 + o * 64 + ks * 32 + quad * 8);
            }
#pragma unroll
            for (int mt = 0; mt < 6; mt++){
                int m = mt * 16 + col;
                int g = m / 12, t = m - 12 * g;
#pragma unroll
                for (int d = 0; d < 3; d++){
                    s16v8 a = *(const s16v8*)&bufX[XIDX(g, t + d, ks * 32 + quad * 8)];
                    aP[mt] = __builtin_amdgcn_mfma_f32_16x16x32_bf16(a, Bf[d][0], aP[mt], 0, 0, 0);
                    aQ[mt] = __builtin_amdgcn_mfma_f32_16x16x32_bf16(a, Bf[d][1], aQ[mt], 0, 0, 0);
                }
            }
        }
        float bP = bf2f(b2[o_p]), bQ = bf2f(b2[o_q]);
#pragma unroll
        for (int mt = 0; mt < 6; mt++){
#pragma unroll
            for (int r = 0; r < 4; r++){
                int m2 = mt * 16 + quad * 4 + r;
                int g = m2 / 12, t = m2 - 12 * g;
                float pv = aP[mt][r] + bP, qv = aQ[mt][r] + bQ;
                bufY[XIDX(g, 1 + t, o_p)] = f2bf(pv / (1.f + __expf(-qv)));
            }
        }
        __syncthreads();
        for (int i = tid; i < 768; i += 256){
            int g = i / 96, r = i % 96, t = r / 8, ch = r % 8;
            *(s16v8*)(outMid + (size_t)(n0 + g) * 768 + t * 64 + ch * 8) =
                *(const s16v8*)&bufY[XIDX(g, 1 + t, ch * 8)];
        }
    } else {
        // ---- final: out[g][o] = sum_k H2[g][k]*fw[o][k] + fb[o] (wave 0; 8 nodes in rows 0..7) ----
        if (wave == 0){
            f32v4 accF = {0.f, 0.f, 0.f, 0.f};
            int g8 = col & 7;
#pragma unroll
            for (int ks = 0; ks < 24; ks++){
                s16v8 a = *(const s16v8*)&bufX[g8 * 1008 + ks * 32 + quad * 8];
                s16v8 bfr = {0, 0, 0, 0, 0, 0, 0, 0};
                if (col < 12)
                    bfr = *(const s16v8*)(fw + (size_t)col * 768 + ks * 32 + quad * 8);
                accF = __builtin_amdgcn_mfma_f32_16x16x32_bf16(a, bfr, accF, 0, 0, 0);
            }
            if (col < 12 && quad < 2){
                float bb = bf2f(fb[col]);
#pragma unroll
                for (int r = 0; r < 4; r++){
                    int g = quad * 4 + r;
                    outFin[(size_t)(n0 + g) * 12 + col] = accF[r] + bb;
                }
            }
        }
    }
}

// ---------------- launch ----------------
static inline size_t align256(size_t x){ return (x + 255) & ~(size_t)255; }

extern "C" void kernel_launch(void* const* d_in, const int* in_sizes, int n_in,
                              void* d_out, int out_size, void* d_ws, size_t ws_size,
                              hipStream_t stream){
    const float* x  = (const float*)d_in[0];
    const int* ei   = (const int*)d_in[1];
    const float* ew = (const float*)d_in[2];

    char* w = (char*)d_ws;
    u16* bufA    = (u16*)w;  w += align256((size_t)N_NODES * 768 * sizeof(u16));
    u16* bufB    = (u16*)w;  w += align256((size_t)N_NODES * 768 * sizeof(u16));
    u16* zA      = (u16*)w;  w += align256((size_t)N_NODES * 768 * sizeof(u16));
    u16* zB      = (u16*)w;  w += align256((size_t)N_NODES * 768 * sizeof(u16));
    float* deg   = (float*)w; w += align256(N_NODES * sizeof(float));
    int* cur     = (int*)w;   w += align256(N_NODES * sizeof(int));
    int2* epack  = (int2*)w;  w += align256((size_t)N_NODES * BUCKET * sizeof(int2));
    u16* cvt     = (u16*)w;   w += align256(104076 * sizeof(u16));

    u16* tc1a_w = cvt + 0;        // [d][128][32]
    u16* tc1a_b = cvt + 12288;
    u16* gc1_w  = cvt + 12416;
    u16* gc1_b  = cvt + 16512;
    u16* tc1b_w = cvt + 16576;    // [d][128][64]
    u16* tc1b_b = cvt + 41152;
    u16* tc2a_w = cvt + 41280;    // [d][128][64]
    u16* tc2a_b = cvt + 65856;
    u16* gc2_w  = cvt + 65984;
    u16* gc2_b  = cvt + 70080;
    u16* tc2b_w = cvt + 70144;    // [d][128][64]
    u16* tc2b_b = cvt + 94720;
    u16* fin_w  = cvt + 94848;
    u16* fin_b  = cvt + 104064;

    SmallPtrs ps;
    ps.p[0]  = d_in[3];  ps.p[1]  = d_in[4];
    ps.p[2]  = d_in[5];  ps.p[3]  = d_in[6];
    ps.p[4]  = d_in[7];  ps.p[5]  = d_in[8];
    ps.p[6]  = d_in[9];  ps.p[7]  = d_in[10];
    ps.p[8]  = d_in[11]; ps.p[9]  = d_in[12];
    ps.p[10] = d_in[13]; ps.p[11] = d_in[14];
    ps.p[12] = d_in[15]; ps.p[13] = d_in[16];

    k_convert_init<<<(104076 + 255) / 256, 256, 0, stream>>>(ps, cvt, deg, cur);
    k_gconv_count<<<1250 + 625, 256, 0, stream>>>(x, tc1a_w, tc1a_b, bufA, ei, ew, deg, cur, epack);
    k_norm<<<(N_NODES * BUCKET) / 256, 256, 0, stream>>>(deg, cur, epack);

    k_gather<<<1250 * 8, 256, 0, stream>>>(bufA, deg, cur, epack, zA);
    k_fused<false><<<1250, 256, 0, stream>>>(zA, gc1_w, gc1_b, tc1b_w, tc1b_b,
                                             tc2a_w, tc2a_b, nullptr, nullptr,
                                             bufB, nullptr);
    k_gather<<<1250 * 8, 256, 0, stream>>>(bufB, deg, cur, epack, zB);
    k_fused<true><<<1250, 256, 0, stream>>>(zB, gc2_w, gc2_b, tc2b_w, tc2b_b,
                                            nullptr, nullptr, fin_w, fin_b,
                                            nullptr, (float*)d_out);
}